// Round 4
// baseline (706.795 us; speedup 1.0000x reference)
//
#include <hip/hip_runtime.h>
#include <math.h>

#define FDIM 256
#define NGRAPH 128
#define NCLASS 10

typedef short short8 __attribute__((ext_vector_type(8)));
typedef float floatx4 __attribute__((ext_vector_type(4)));

// fp32 <-> bf16 helpers (RNE)
static __device__ __forceinline__ unsigned short f2bf(float f) {
    unsigned u = __float_as_uint(f);
    u += 0x7FFF + ((u >> 16) & 1);
    return (unsigned short)(u >> 16);
}
static __device__ __forceinline__ float bf2f(unsigned short h) {
    return __uint_as_float(((unsigned)h) << 16);
}

// ---------------- CSR build ----------------

__global__ void count_kernel(const int* __restrict__ dst, int* __restrict__ cnt, int E) {
    int e = blockIdx.x * blockDim.x + threadIdx.x;
    if (e < E) atomicAdd(&cnt[dst[e]], 1);
}

// exclusive scan cnt -> rowptr, plus dinv = rsqrt(cnt+1), single block
__global__ __launch_bounds__(1024) void scan_kernel(const int* __restrict__ cnt,
                                                    int* __restrict__ rowptr,
                                                    float* __restrict__ dinv, int N, int E) {
    __shared__ int sums[1024];
    const int t = threadIdx.x;
    const int chunk = (N + 1023) / 1024;
    const int beg = t * chunk;
    const int end = min(beg + chunk, N);
    int s = 0;
    for (int i = beg; i < end; i++) s += cnt[i];
    sums[t] = s;
    __syncthreads();
    for (int off = 1; off < 1024; off <<= 1) {
        int v = (t >= off) ? sums[t - off] : 0;
        __syncthreads();
        sums[t] += v;
        __syncthreads();
    }
    int run = (t == 0) ? 0 : sums[t - 1];
    for (int i = beg; i < end; i++) {
        rowptr[i] = run;
        int c = cnt[i];
        run += c;
        dinv[i] = rsqrtf((float)c + 1.0f);   // +1 = self loop
    }
    if (t == 1023) rowptr[N] = E;
}

__global__ void fill_kernel(const int* __restrict__ src, const int* __restrict__ dst,
                            const int* __restrict__ rowptr, int* __restrict__ cursor,
                            int* __restrict__ srcs, int E) {
    int e = blockIdx.x * blockDim.x + threadIdx.x;
    if (e < E) {
        int d = dst[e];
        int pos = atomicAdd(&cursor[d], 1);
        srcs[rowptr[d] + pos] = src[e];
    }
}

// ---------------- fp32 -> bf16 cast ----------------

__global__ __launch_bounds__(256) void cast_kernel(const float4* __restrict__ in,
                                                   unsigned short* __restrict__ out, int n4) {
    int i = blockIdx.x * blockDim.x + threadIdx.x;
    if (i < n4) {
        float4 v = in[i];
        unsigned short o[4] = {f2bf(v.x), f2bf(v.y), f2bf(v.z), f2bf(v.w)};
        *(uint2*)(out + (size_t)i * 4) = *(uint2*)o;
    }
}

// ---------------- weight pack: fragment-ordered bf16 ----------------
// Bpack[((kstep*16 + ntile)*64 + lane)*8 + j] = W[kstep*32 + (lane>>4)*8 + j][ntile*16 + (lane&15)]

__global__ __launch_bounds__(256) void packw_kernel(const float* __restrict__ W,
                                                    unsigned short* __restrict__ Bp) {
    int idx = blockIdx.x * blockDim.x + threadIdx.x;   // [0, 8192)
    int kstep = idx >> 10;
    int ntile = (idx >> 6) & 15;
    int lane  = idx & 63;
    int col   = ntile * 16 + (lane & 15);
    int krow  = kstep * 32 + (lane >> 4) * 8;
    unsigned short o[8];
#pragma unroll
    for (int j = 0; j < 8; j++) o[j] = f2bf(W[(size_t)(krow + j) * FDIM + col]);
    *(uint4*)(Bp + (size_t)idx * 8) = *(uint4*)o;
}

// ---------------- bf16 MFMA GEMM: C[M,256] = A[M,256] @ W ----------------
// block = 4 waves; wave -> 16 rows x full 256 cols (16 n-tiles). A read once.

__global__ __launch_bounds__(256) void mfma_gemm(const unsigned short* __restrict__ A,
                                                 const unsigned short* __restrict__ Bp,
                                                 unsigned short* __restrict__ C, int M) {
    const int wave = threadIdx.x >> 6;
    const int lane = threadIdx.x & 63;
    const int quad = lane >> 4;
    const int m    = lane & 15;
    const int row0 = blockIdx.x * 64 + wave * 16;

    const short* arow = (const short*)A + (size_t)(row0 + m) * FDIM + quad * 8;

    floatx4 acc[16];
#pragma unroll
    for (int i = 0; i < 16; i++) acc[i] = (floatx4){0.f, 0.f, 0.f, 0.f};

#pragma unroll
    for (int kstep = 0; kstep < 8; kstep++) {
        short8 a = *(const short8*)(arow + kstep * 32);
#pragma unroll
        for (int nt = 0; nt < 16; nt++) {
            short8 b = *(const short8*)((const short*)Bp +
                         ((size_t)(kstep * 16 + nt) * 64 + lane) * 8);
            acc[nt] = __builtin_amdgcn_mfma_f32_16x16x32_bf16(a, b, acc[nt], 0, 0, 0);
        }
    }

    // C/D layout: col = lane&15, row = quad*4 + r
#pragma unroll
    for (int nt = 0; nt < 16; nt++) {
        int col = nt * 16 + m;
#pragma unroll
        for (int r = 0; r < 4; r++) {
            int row = row0 + quad * 4 + r;
            if (row < M) C[(size_t)row * FDIM + col] = f2bf(acc[nt][r]);
        }
    }
}

// ---------------- fused gather + self-loop + bias + relu (bf16 state) ----------------
// half-wave (32 lanes) per dst node; lane = 8 feats (16B). Edge loop unrolled x4 for MLP.

static __device__ __forceinline__ void accum8(float* acc, uint4 v, float nm) {
    const unsigned* u = (const unsigned*)&v;
#pragma unroll
    for (int i = 0; i < 4; i++) {
        acc[2 * i]     += nm * __uint_as_float(u[i] << 16);
        acc[2 * i + 1] += nm * __uint_as_float(u[i] & 0xFFFF0000u);
    }
}

__global__ __launch_bounds__(256) void gather_kernel(const unsigned short* __restrict__ h,
                                                     const int* __restrict__ rowptr,
                                                     const int* __restrict__ srcs,
                                                     const float* __restrict__ dinv,
                                                     const float* __restrict__ bias,
                                                     unsigned short* __restrict__ out, int N) {
    const int node = blockIdx.x * 8 + (threadIdx.x >> 5);
    const int lane = threadIdx.x & 31;
    if (node >= N) return;
    const float di = dinv[node];

    float acc[8];
    {
        uint4 sv = *(const uint4*)(h + (size_t)node * FDIM + lane * 8);
        const unsigned* u = (const unsigned*)&sv;
#pragma unroll
        for (int i = 0; i < 4; i++) {
            acc[2 * i]     = di * di * __uint_as_float(u[i] << 16);
            acc[2 * i + 1] = di * di * __uint_as_float(u[i] & 0xFFFF0000u);
        }
        float4 b0 = *(const float4*)(bias + lane * 8);
        float4 b1 = *(const float4*)(bias + lane * 8 + 4);
        acc[0] += b0.x; acc[1] += b0.y; acc[2] += b0.z; acc[3] += b0.w;
        acc[4] += b1.x; acc[5] += b1.y; acc[6] += b1.z; acc[7] += b1.w;
    }

    const int beg = rowptr[node];
    const int end = rowptr[node + 1];
    int p = beg;
    for (; p + 4 <= end; p += 4) {
        int s0 = srcs[p], s1 = srcs[p + 1], s2 = srcs[p + 2], s3 = srcs[p + 3];
        float n0 = dinv[s0] * di, n1 = dinv[s1] * di;
        float n2 = dinv[s2] * di, n3 = dinv[s3] * di;
        uint4 v0 = *(const uint4*)(h + (size_t)s0 * FDIM + lane * 8);
        uint4 v1 = *(const uint4*)(h + (size_t)s1 * FDIM + lane * 8);
        uint4 v2 = *(const uint4*)(h + (size_t)s2 * FDIM + lane * 8);
        uint4 v3 = *(const uint4*)(h + (size_t)s3 * FDIM + lane * 8);
        accum8(acc, v0, n0);
        accum8(acc, v1, n1);
        accum8(acc, v2, n2);
        accum8(acc, v3, n3);
    }
    for (; p < end; p++) {
        int s = srcs[p];
        float nm = dinv[s] * di;
        uint4 v = *(const uint4*)(h + (size_t)s * FDIM + lane * 8);
        accum8(acc, v, nm);
    }

    unsigned short o[8];
#pragma unroll
    for (int i = 0; i < 8; i++) o[i] = f2bf(fmaxf(acc[i], 0.0f));
    *(uint4*)(out + (size_t)node * FDIM + lane * 8) = *(uint4*)o;
}

// ---------------- fused head: pool + FC1 + relu + FC2 + log_softmax ----------------
// one block per graph; batch sorted -> binary search node range. No atomics.

__global__ __launch_bounds__(256) void head_kernel(const unsigned short* __restrict__ state,
                                                   const int* __restrict__ batch,
                                                   const float* __restrict__ fc1W,
                                                   const float* __restrict__ fc1b,
                                                   const float* __restrict__ fc2W,
                                                   const float* __restrict__ fc2b,
                                                   float* __restrict__ out, int N) {
    __shared__ float gs[FDIM];
    __shared__ float hs[FDIM];
    __shared__ float logits[NCLASS];
    __shared__ int range[2];
    const int gId = blockIdx.x;
    const int t = threadIdx.x;

    if (t < 2) {
        int target = gId + t;          // lower_bound(batch, target)
        int lo = 0, hi = N;
        while (lo < hi) {
            int mid = (lo + hi) >> 1;
            if (batch[mid] < target) lo = mid + 1; else hi = mid;
        }
        range[t] = lo;
    }
    __syncthreads();
    const int s = range[0], e = range[1];

    float acc = 0.0f;
    for (int n = s; n < e; n++) acc += bf2f(state[(size_t)n * FDIM + t]);
    gs[t] = acc;
    __syncthreads();

    float a1 = fc1b[t];
    for (int k = 0; k < FDIM; k++) a1 += gs[k] * fc1W[(size_t)k * FDIM + t];
    hs[t] = fmaxf(a1, 0.0f);
    __syncthreads();

    if (t < NCLASS) {
        float a2 = fc2b[t];
        for (int k = 0; k < FDIM; k++) a2 += hs[k] * fc2W[(size_t)k * NCLASS + t];
        logits[t] = a2;
    }
    __syncthreads();

    if (t == 0) {
        float mx = logits[0];
        for (int c = 1; c < NCLASS; c++) mx = fmaxf(mx, logits[c]);
        float ssum = 0.0f;
        for (int c = 0; c < NCLASS; c++) ssum += expf(logits[c] - mx);
        float lse = mx + logf(ssum);
        for (int c = 0; c < NCLASS; c++) out[(size_t)gId * NCLASS + c] = logits[c] - lse;
    }
}

// ---------------- launcher ----------------

extern "C" void kernel_launch(void* const* d_in, const int* in_sizes, int n_in,
                              void* d_out, int out_size, void* d_ws, size_t ws_size,
                              hipStream_t stream) {
    const float* x     = (const float*)d_in[0];
    const int*   ei    = (const int*)d_in[1];
    const int*   batch = (const int*)d_in[2];
    const float* W0 = (const float*)d_in[3];  const float* b0 = (const float*)d_in[4];
    const float* W1 = (const float*)d_in[5];  const float* b1 = (const float*)d_in[6];
    const float* W2 = (const float*)d_in[7];  const float* b2 = (const float*)d_in[8];
    const float* fc1W = (const float*)d_in[9];  const float* fc1b = (const float*)d_in[10];
    const float* fc2W = (const float*)d_in[11]; const float* fc2b = (const float*)d_in[12];
    float* out = (float*)d_out;

    const int N = in_sizes[0] / FDIM;
    const int E = in_sizes[1] / 2;
    const int* src = ei;
    const int* dst = ei + E;
    const int Mpad = ((N + 63) / 64) * 64;

    // workspace layout (16B-aligned chunks)
    char* p = (char*)d_ws;
    unsigned short* S0 = (unsigned short*)p; p += (size_t)Mpad * FDIM * 2;  // node state A
    unsigned short* S1 = (unsigned short*)p; p += (size_t)Mpad * FDIM * 2;  // node state B
    unsigned short* H  = (unsigned short*)p; p += (size_t)Mpad * FDIM * 2;  // GEMM out
    unsigned short* Wp0 = (unsigned short*)p; p += (size_t)8192 * 8 * 2;
    unsigned short* Wp1 = (unsigned short*)p; p += (size_t)8192 * 8 * 2;
    unsigned short* Wp2 = (unsigned short*)p; p += (size_t)8192 * 8 * 2;
    float* dinv = (float*)p; p += (size_t)N * 4;
    int*   cnt  = (int*)p;   p += (size_t)N * 4;        // reused as fill cursor
    int*   rowptr = (int*)p; p += (size_t)(N + 4) * 4;
    int*   srcs = (int*)p;

    // ---- CSR build ----
    hipMemsetAsync(cnt, 0, (size_t)N * sizeof(int), stream);
    count_kernel<<<(E + 255) / 256, 256, 0, stream>>>(dst, cnt, E);
    scan_kernel<<<1, 1024, 0, stream>>>(cnt, rowptr, dinv, N, E);
    hipMemsetAsync(cnt, 0, (size_t)N * sizeof(int), stream);
    fill_kernel<<<(E + 255) / 256, 256, 0, stream>>>(src, dst, rowptr, cnt, srcs, E);

    // ---- casts / weight packs ----
    cast_kernel<<<((N * FDIM / 4) + 255) / 256, 256, 0, stream>>>((const float4*)x, S0, N * FDIM / 4);
    packw_kernel<<<32, 256, 0, stream>>>(W0, Wp0);
    packw_kernel<<<32, 256, 0, stream>>>(W1, Wp1);
    packw_kernel<<<32, 256, 0, stream>>>(W2, Wp2);

    // ---- 3 GCN layers ----
    const unsigned short* Wps[3] = {Wp0, Wp1, Wp2};
    const float* bs[3] = {b0, b1, b2};
    unsigned short* states[4] = {S0, S1, S0, S1};
    for (int l = 0; l < 3; l++) {
        mfma_gemm<<<(N + 63) / 64, 256, 0, stream>>>(states[l], Wps[l], H, N);
        gather_kernel<<<(N + 7) / 8, 256, 0, stream>>>(H, rowptr, srcs, dinv, bs[l],
                                                       states[l + 1], N);
    }

    // ---- fused head ----
    head_kernel<<<NGRAPH, 256, 0, stream>>>(states[3], batch, fc1W, fc1b, fc2W, fc2b, out, N);
}

// Round 5
// 630.465 us; speedup vs baseline: 1.1211x; 1.1211x over previous
//
#include <hip/hip_runtime.h>
#include <math.h>

#define FDIM 256
#define NGRAPH 128
#define NCLASS 10

typedef short short8 __attribute__((ext_vector_type(8)));
typedef float floatx4 __attribute__((ext_vector_type(4)));

// fp32 <-> bf16 helpers (RNE)
static __device__ __forceinline__ unsigned short f2bf(float f) {
    unsigned u = __float_as_uint(f);
    u += 0x7FFF + ((u >> 16) & 1);
    return (unsigned short)(u >> 16);
}
static __device__ __forceinline__ float bf2f(unsigned short h) {
    return __uint_as_float(((unsigned)h) << 16);
}

// ---------------- CSR build ----------------

__global__ void count_kernel(const int* __restrict__ dst, int* __restrict__ cnt, int E) {
    int e = blockIdx.x * blockDim.x + threadIdx.x;
    if (e < E) atomicAdd(&cnt[dst[e]], 1);
}

// exclusive scan cnt -> rowptr, plus dinv = rsqrt(cnt+1), single block
__global__ __launch_bounds__(1024) void scan_kernel(const int* __restrict__ cnt,
                                                    int* __restrict__ rowptr,
                                                    float* __restrict__ dinv, int N, int E) {
    __shared__ int sums[1024];
    const int t = threadIdx.x;
    const int chunk = (N + 1023) / 1024;
    const int beg = t * chunk;
    const int end = min(beg + chunk, N);
    int s = 0;
    for (int i = beg; i < end; i++) s += cnt[i];
    sums[t] = s;
    __syncthreads();
    for (int off = 1; off < 1024; off <<= 1) {
        int v = (t >= off) ? sums[t - off] : 0;
        __syncthreads();
        sums[t] += v;
        __syncthreads();
    }
    int run = (t == 0) ? 0 : sums[t - 1];
    for (int i = beg; i < end; i++) {
        rowptr[i] = run;
        int c = cnt[i];
        run += c;
        dinv[i] = rsqrtf((float)c + 1.0f);   // +1 = self loop
    }
    if (t == 1023) rowptr[N] = E;
}

__global__ void fill_kernel(const int* __restrict__ src, const int* __restrict__ dst,
                            const int* __restrict__ rowptr, int* __restrict__ cursor,
                            int* __restrict__ srcs, int E) {
    int e = blockIdx.x * blockDim.x + threadIdx.x;
    if (e < E) {
        int d = dst[e];
        int pos = atomicAdd(&cursor[d], 1);
        srcs[rowptr[d] + pos] = src[e];
    }
}

// ---------------- fp32 -> bf16 cast ----------------

__global__ __launch_bounds__(256) void cast_kernel(const float4* __restrict__ in,
                                                   unsigned short* __restrict__ out, int n4) {
    int i = blockIdx.x * blockDim.x + threadIdx.x;
    if (i < n4) {
        float4 v = in[i];
        unsigned short o[4] = {f2bf(v.x), f2bf(v.y), f2bf(v.z), f2bf(v.w)};
        *(uint2*)(out + (size_t)i * 4) = *(uint2*)o;
    }
}

// ---------------- weight pack: fragment-ordered bf16 ----------------
// Bpack[((kstep*16 + ntile)*64 + lane)*8 + j] = W[kstep*32 + (lane>>4)*8 + j][ntile*16 + (lane&15)]

__global__ __launch_bounds__(256) void packw_kernel(const float* __restrict__ W,
                                                    unsigned short* __restrict__ Bp) {
    int idx = blockIdx.x * blockDim.x + threadIdx.x;   // [0, 8192)
    int kstep = idx >> 10;
    int ntile = (idx >> 6) & 15;
    int lane  = idx & 63;
    int col   = ntile * 16 + (lane & 15);
    int krow  = kstep * 32 + (lane >> 4) * 8;
    unsigned short o[8];
#pragma unroll
    for (int j = 0; j < 8; j++) o[j] = f2bf(W[(size_t)(krow + j) * FDIM + col]);
    *(uint4*)(Bp + (size_t)idx * 8) = *(uint4*)o;
}

// ---------------- bf16 MFMA GEMM: C[M,256] = A[M,256] @ W ----------------
// block = 4 waves; wave -> 16 rows x full 256 cols (16 n-tiles). A read once.

__global__ __launch_bounds__(256) void mfma_gemm(const unsigned short* __restrict__ A,
                                                 const unsigned short* __restrict__ Bp,
                                                 unsigned short* __restrict__ C, int M) {
    const int wave = threadIdx.x >> 6;
    const int lane = threadIdx.x & 63;
    const int quad = lane >> 4;
    const int m    = lane & 15;
    const int row0 = blockIdx.x * 64 + wave * 16;

    const short* arow = (const short*)A + (size_t)(row0 + m) * FDIM + quad * 8;

    floatx4 acc[16];
#pragma unroll
    for (int i = 0; i < 16; i++) acc[i] = (floatx4){0.f, 0.f, 0.f, 0.f};

#pragma unroll
    for (int kstep = 0; kstep < 8; kstep++) {
        short8 a = *(const short8*)(arow + kstep * 32);
#pragma unroll
        for (int nt = 0; nt < 16; nt++) {
            short8 b = *(const short8*)((const short*)Bp +
                         ((size_t)(kstep * 16 + nt) * 64 + lane) * 8);
            acc[nt] = __builtin_amdgcn_mfma_f32_16x16x32_bf16(a, b, acc[nt], 0, 0, 0);
        }
    }

    // C/D layout: col = lane&15, row = quad*4 + r
#pragma unroll
    for (int nt = 0; nt < 16; nt++) {
        int col = nt * 16 + m;
#pragma unroll
        for (int r = 0; r < 4; r++) {
            int row = row0 + quad * 4 + r;
            if (row < M) C[(size_t)row * FDIM + col] = f2bf(acc[nt][r]);
        }
    }
}

// ---------------- fused gather + self-loop + bias + relu (bf16 state) ----------------
// half-wave (32 lanes) per dst node; lane = 8 feats (16B). Edge loop unrolled x4 for MLP.

static __device__ __forceinline__ void accum8(float* acc, uint4 v, float nm) {
    const unsigned* u = (const unsigned*)&v;
#pragma unroll
    for (int i = 0; i < 4; i++) {
        acc[2 * i]     += nm * __uint_as_float(u[i] << 16);
        acc[2 * i + 1] += nm * __uint_as_float(u[i] & 0xFFFF0000u);
    }
}

__global__ __launch_bounds__(256) void gather_kernel(const unsigned short* __restrict__ h,
                                                     const int* __restrict__ rowptr,
                                                     const int* __restrict__ srcs,
                                                     const float* __restrict__ dinv,
                                                     const float* __restrict__ bias,
                                                     unsigned short* __restrict__ out, int N) {
    const int node = blockIdx.x * 8 + (threadIdx.x >> 5);
    const int lane = threadIdx.x & 31;
    if (node >= N) return;
    const float di = dinv[node];

    float acc[8];
    {
        uint4 sv = *(const uint4*)(h + (size_t)node * FDIM + lane * 8);
        const unsigned* u = (const unsigned*)&sv;
#pragma unroll
        for (int i = 0; i < 4; i++) {
            acc[2 * i]     = di * di * __uint_as_float(u[i] << 16);
            acc[2 * i + 1] = di * di * __uint_as_float(u[i] & 0xFFFF0000u);
        }
        float4 b0 = *(const float4*)(bias + lane * 8);
        float4 b1 = *(const float4*)(bias + lane * 8 + 4);
        acc[0] += b0.x; acc[1] += b0.y; acc[2] += b0.z; acc[3] += b0.w;
        acc[4] += b1.x; acc[5] += b1.y; acc[6] += b1.z; acc[7] += b1.w;
    }

    const int beg = rowptr[node];
    const int end = rowptr[node + 1];
    int p = beg;
    for (; p + 4 <= end; p += 4) {
        int s0 = srcs[p], s1 = srcs[p + 1], s2 = srcs[p + 2], s3 = srcs[p + 3];
        float n0 = dinv[s0] * di, n1 = dinv[s1] * di;
        float n2 = dinv[s2] * di, n3 = dinv[s3] * di;
        uint4 v0 = *(const uint4*)(h + (size_t)s0 * FDIM + lane * 8);
        uint4 v1 = *(const uint4*)(h + (size_t)s1 * FDIM + lane * 8);
        uint4 v2 = *(const uint4*)(h + (size_t)s2 * FDIM + lane * 8);
        uint4 v3 = *(const uint4*)(h + (size_t)s3 * FDIM + lane * 8);
        accum8(acc, v0, n0);
        accum8(acc, v1, n1);
        accum8(acc, v2, n2);
        accum8(acc, v3, n3);
    }
    for (; p < end; p++) {
        int s = srcs[p];
        float nm = dinv[s] * di;
        uint4 v = *(const uint4*)(h + (size_t)s * FDIM + lane * 8);
        accum8(acc, v, nm);
    }

    unsigned short o[8];
#pragma unroll
    for (int i = 0; i < 8; i++) o[i] = f2bf(fmaxf(acc[i], 0.0f));
    *(uint4*)(out + (size_t)node * FDIM + lane * 8) = *(uint4*)o;
}

// ---------------- global add pool (bf16 state; batch sorted; run-length atomics) ----------------

__global__ __launch_bounds__(256) void pool_kernel(const unsigned short* __restrict__ state,
                                                   const int* __restrict__ batch,
                                                   float* __restrict__ g, int N) {
    int n0 = blockIdx.x * 16;
    int f = threadIdx.x;
    int cur = -1;
    float run = 0.0f;
    for (int i = 0; i < 16; i++) {
        int n = n0 + i;
        if (n >= N) break;
        int b = batch[n];
        if (b != cur) {
            if (cur >= 0) atomicAdd(&g[(size_t)cur * FDIM + f], run);
            cur = b;
            run = 0.0f;
        }
        run += bf2f(state[(size_t)n * FDIM + f]);
    }
    if (cur >= 0) atomicAdd(&g[(size_t)cur * FDIM + f], run);
}

// ---------------- fused FC head: FC1 + relu + FC2 + log_softmax ----------------
// one block per graph (pool already done in parallel).

__global__ __launch_bounds__(256) void fc_head_kernel(const float* __restrict__ g,
                                                      const float* __restrict__ fc1W,
                                                      const float* __restrict__ fc1b,
                                                      const float* __restrict__ fc2W,
                                                      const float* __restrict__ fc2b,
                                                      float* __restrict__ out) {
    __shared__ float gs[FDIM];
    __shared__ float hs[FDIM];
    __shared__ float logits[NCLASS];
    const int r = blockIdx.x;
    const int t = threadIdx.x;

    gs[t] = g[(size_t)r * FDIM + t];
    __syncthreads();

    float a1 = fc1b[t];
    for (int k = 0; k < FDIM; k++) a1 += gs[k] * fc1W[(size_t)k * FDIM + t];
    hs[t] = fmaxf(a1, 0.0f);
    __syncthreads();

    if (t < NCLASS) {
        float a2 = fc2b[t];
        for (int k = 0; k < FDIM; k++) a2 += hs[k] * fc2W[(size_t)k * NCLASS + t];
        logits[t] = a2;
    }
    __syncthreads();

    if (t == 0) {
        float mx = logits[0];
        for (int c = 1; c < NCLASS; c++) mx = fmaxf(mx, logits[c]);
        float ssum = 0.0f;
        for (int c = 0; c < NCLASS; c++) ssum += expf(logits[c] - mx);
        float lse = mx + logf(ssum);
        for (int c = 0; c < NCLASS; c++) out[(size_t)r * NCLASS + c] = logits[c] - lse;
    }
}

// ---------------- launcher ----------------

extern "C" void kernel_launch(void* const* d_in, const int* in_sizes, int n_in,
                              void* d_out, int out_size, void* d_ws, size_t ws_size,
                              hipStream_t stream) {
    const float* x     = (const float*)d_in[0];
    const int*   ei    = (const int*)d_in[1];
    const int*   batch = (const int*)d_in[2];
    const float* W0 = (const float*)d_in[3];  const float* b0 = (const float*)d_in[4];
    const float* W1 = (const float*)d_in[5];  const float* b1 = (const float*)d_in[6];
    const float* W2 = (const float*)d_in[7];  const float* b2 = (const float*)d_in[8];
    const float* fc1W = (const float*)d_in[9];  const float* fc1b = (const float*)d_in[10];
    const float* fc2W = (const float*)d_in[11]; const float* fc2b = (const float*)d_in[12];
    float* out = (float*)d_out;

    const int N = in_sizes[0] / FDIM;
    const int E = in_sizes[1] / 2;
    const int* src = ei;
    const int* dst = ei + E;
    const int Mpad = ((N + 63) / 64) * 64;

    // workspace layout (16B-aligned chunks)
    char* p = (char*)d_ws;
    unsigned short* S0 = (unsigned short*)p; p += (size_t)Mpad * FDIM * 2;  // node state A
    unsigned short* S1 = (unsigned short*)p; p += (size_t)Mpad * FDIM * 2;  // node state B
    unsigned short* H  = (unsigned short*)p; p += (size_t)Mpad * FDIM * 2;  // GEMM out
    unsigned short* Wp0 = (unsigned short*)p; p += (size_t)8192 * 8 * 2;
    unsigned short* Wp1 = (unsigned short*)p; p += (size_t)8192 * 8 * 2;
    unsigned short* Wp2 = (unsigned short*)p; p += (size_t)8192 * 8 * 2;
    float* dinv = (float*)p; p += (size_t)N * 4;
    int*   cnt  = (int*)p;   p += (size_t)N * 4;        // reused as fill cursor
    int*   rowptr = (int*)p; p += (size_t)(N + 4) * 4;
    int*   srcs = (int*)p;   p += (size_t)E * 4;
    float* g    = (float*)p;

    // ---- CSR build ----
    hipMemsetAsync(cnt, 0, (size_t)N * sizeof(int), stream);
    count_kernel<<<(E + 255) / 256, 256, 0, stream>>>(dst, cnt, E);
    scan_kernel<<<1, 1024, 0, stream>>>(cnt, rowptr, dinv, N, E);
    hipMemsetAsync(cnt, 0, (size_t)N * sizeof(int), stream);
    fill_kernel<<<(E + 255) / 256, 256, 0, stream>>>(src, dst, rowptr, cnt, srcs, E);

    // ---- casts / weight packs ----
    cast_kernel<<<((N * FDIM / 4) + 255) / 256, 256, 0, stream>>>((const float4*)x, S0, N * FDIM / 4);
    packw_kernel<<<32, 256, 0, stream>>>(W0, Wp0);
    packw_kernel<<<32, 256, 0, stream>>>(W1, Wp1);
    packw_kernel<<<32, 256, 0, stream>>>(W2, Wp2);

    // ---- 3 GCN layers ----
    const unsigned short* Wps[3] = {Wp0, Wp1, Wp2};
    const float* bs[3] = {b0, b1, b2};
    unsigned short* states[4] = {S0, S1, S0, S1};
    for (int l = 0; l < 3; l++) {
        mfma_gemm<<<(N + 63) / 64, 256, 0, stream>>>(states[l], Wps[l], H, N);
        gather_kernel<<<(N + 7) / 8, 256, 0, stream>>>(H, rowptr, srcs, dinv, bs[l],
                                                       states[l + 1], N);
    }

    // ---- head ----
    hipMemsetAsync(g, 0, (size_t)NGRAPH * FDIM * sizeof(float), stream);
    pool_kernel<<<(N + 15) / 16, 256, 0, stream>>>(states[3], batch, g, N);
    fc_head_kernel<<<NGRAPH, 256, 0, stream>>>(g, fc1W, fc1b, fc2W, fc2b, out);
}

// Round 6
// 532.923 us; speedup vs baseline: 1.3263x; 1.1830x over previous
//
#include <hip/hip_runtime.h>
#include <math.h>

#define FDIM 256
#define NGRAPH 128
#define NCLASS 10

typedef short short8 __attribute__((ext_vector_type(8)));
typedef float floatx4 __attribute__((ext_vector_type(4)));

// fp32 <-> bf16 helpers (RNE)
static __device__ __forceinline__ unsigned short f2bf(float f) {
    unsigned u = __float_as_uint(f);
    u += 0x7FFF + ((u >> 16) & 1);
    return (unsigned short)(u >> 16);
}
static __device__ __forceinline__ float bf2f(unsigned short h) {
    return __uint_as_float(((unsigned)h) << 16);
}

// ---------------- CSR build ----------------

__global__ void count_kernel(const int* __restrict__ dst, int* __restrict__ cnt, int E) {
    int e = blockIdx.x * blockDim.x + threadIdx.x;
    if (e < E) atomicAdd(&cnt[dst[e]], 1);
}

// stage 1: per-block (1024-elem) sums of cnt
__global__ __launch_bounds__(256) void csr_bsum(const int* __restrict__ cnt,
                                                int* __restrict__ bsum, int N) {
    __shared__ int red[256];
    const int t = threadIdx.x;
    const int base = blockIdx.x * 1024 + t * 4;
    int s = 0;
#pragma unroll
    for (int i = 0; i < 4; i++)
        if (base + i < N) s += cnt[base + i];
    red[t] = s;
    __syncthreads();
    for (int off = 128; off > 0; off >>= 1) {
        if (t < off) red[t] += red[t + off];
        __syncthreads();
    }
    if (t == 0) bsum[blockIdx.x] = red[0];
}

// stage 2: exclusive scan of bsum (nb <= 256), in place
__global__ __launch_bounds__(256) void csr_bscan(int* __restrict__ bsum, int nb) {
    __shared__ int s[256];
    const int t = threadIdx.x;
    if (t < nb) s[t] = bsum[t];
    __syncthreads();
    if (t == 0) {
        int run = 0;
        for (int i = 0; i < nb; i++) { int v = s[i]; s[i] = run; run += v; }
    }
    __syncthreads();
    if (t < nb) bsum[t] = s[t];
}

// stage 3: block-local scan + block offset -> rowptr; dinv = rsqrt(cnt+1)
__global__ __launch_bounds__(256) void csr_scan2(const int* __restrict__ cnt,
                                                 const int* __restrict__ boff,
                                                 int* __restrict__ rowptr,
                                                 float* __restrict__ dinv, int N, int E) {
    __shared__ int tsum[256];
    const int t = threadIdx.x;
    const int base = blockIdx.x * 1024 + t * 4;
    int c[4];
    int s = 0;
#pragma unroll
    for (int i = 0; i < 4; i++) {
        c[i] = (base + i < N) ? cnt[base + i] : 0;
        s += c[i];
    }
    tsum[t] = s;
    __syncthreads();
    for (int off = 1; off < 256; off <<= 1) {
        int v = (t >= off) ? tsum[t - off] : 0;
        __syncthreads();
        tsum[t] += v;
        __syncthreads();
    }
    int run = boff[blockIdx.x] + ((t == 0) ? 0 : tsum[t - 1]);
#pragma unroll
    for (int i = 0; i < 4; i++) {
        int idx = base + i;
        if (idx < N) {
            rowptr[idx] = run;
            dinv[idx] = rsqrtf((float)c[i] + 1.0f);   // +1 = self loop
            run += c[i];
        }
    }
    if (blockIdx.x == 0 && t == 0) rowptr[N] = E;
}

__global__ void fill_kernel(const int* __restrict__ src, const int* __restrict__ dst,
                            const int* __restrict__ rowptr, int* __restrict__ cursor,
                            int* __restrict__ srcs, int E) {
    int e = blockIdx.x * blockDim.x + threadIdx.x;
    if (e < E) {
        int d = dst[e];
        int pos = atomicAdd(&cursor[d], 1);
        srcs[rowptr[d] + pos] = src[e];
    }
}

// ---------------- fp32 -> bf16 cast ----------------

__global__ __launch_bounds__(256) void cast_kernel(const float4* __restrict__ in,
                                                   unsigned short* __restrict__ out, int n4) {
    int i = blockIdx.x * blockDim.x + threadIdx.x;
    if (i < n4) {
        float4 v = in[i];
        unsigned short o[4] = {f2bf(v.x), f2bf(v.y), f2bf(v.z), f2bf(v.w)};
        *(uint2*)(out + (size_t)i * 4) = *(uint2*)o;
    }
}

// ---------------- weight pack: fragment-ordered bf16 ----------------
// Bpack[((kstep*16 + ntile)*64 + lane)*8 + j] = W[kstep*32 + (lane>>4)*8 + j][ntile*16 + (lane&15)]

__global__ __launch_bounds__(256) void packw_kernel(const float* __restrict__ W,
                                                    unsigned short* __restrict__ Bp) {
    int idx = blockIdx.x * blockDim.x + threadIdx.x;   // [0, 8192)
    int kstep = idx >> 10;
    int ntile = (idx >> 6) & 15;
    int lane  = idx & 63;
    int col   = ntile * 16 + (lane & 15);
    int krow  = kstep * 32 + (lane >> 4) * 8;
    unsigned short o[8];
#pragma unroll
    for (int j = 0; j < 8; j++) o[j] = f2bf(W[(size_t)(krow + j) * FDIM + col]);
    *(uint4*)(Bp + (size_t)idx * 8) = *(uint4*)o;
}

// ---------------- bf16 MFMA GEMM: C[M,256] = A[M,256] @ W ----------------
// block = 4 waves; wave -> 16 rows x full 256 cols (16 n-tiles). A read once.

__global__ __launch_bounds__(256) void mfma_gemm(const unsigned short* __restrict__ A,
                                                 const unsigned short* __restrict__ Bp,
                                                 unsigned short* __restrict__ C, int M) {
    const int wave = threadIdx.x >> 6;
    const int lane = threadIdx.x & 63;
    const int quad = lane >> 4;
    const int m    = lane & 15;
    const int row0 = blockIdx.x * 64 + wave * 16;

    const short* arow = (const short*)A + (size_t)(row0 + m) * FDIM + quad * 8;

    floatx4 acc[16];
#pragma unroll
    for (int i = 0; i < 16; i++) acc[i] = (floatx4){0.f, 0.f, 0.f, 0.f};

#pragma unroll
    for (int kstep = 0; kstep < 8; kstep++) {
        short8 a = *(const short8*)(arow + kstep * 32);
#pragma unroll
        for (int nt = 0; nt < 16; nt++) {
            short8 b = *(const short8*)((const short*)Bp +
                         ((size_t)(kstep * 16 + nt) * 64 + lane) * 8);
            acc[nt] = __builtin_amdgcn_mfma_f32_16x16x32_bf16(a, b, acc[nt], 0, 0, 0);
        }
    }

    // C/D layout: col = lane&15, row = quad*4 + r
#pragma unroll
    for (int nt = 0; nt < 16; nt++) {
        int col = nt * 16 + m;
#pragma unroll
        for (int r = 0; r < 4; r++) {
            int row = row0 + quad * 4 + r;
            if (row < M) C[(size_t)row * FDIM + col] = f2bf(acc[nt][r]);
        }
    }
}

// ---------------- fused gather + self-loop + bias + relu (bf16 state) ----------------
// half-wave (32 lanes) per dst node; lane = 8 feats (16B). Edge loop unrolled x4 for MLP.

static __device__ __forceinline__ void accum8(float* acc, uint4 v, float nm) {
    const unsigned* u = (const unsigned*)&v;
#pragma unroll
    for (int i = 0; i < 4; i++) {
        acc[2 * i]     += nm * __uint_as_float(u[i] << 16);
        acc[2 * i + 1] += nm * __uint_as_float(u[i] & 0xFFFF0000u);
    }
}

__global__ __launch_bounds__(256) void gather_kernel(const unsigned short* __restrict__ h,
                                                     const int* __restrict__ rowptr,
                                                     const int* __restrict__ srcs,
                                                     const float* __restrict__ dinv,
                                                     const float* __restrict__ bias,
                                                     unsigned short* __restrict__ out, int N) {
    const int node = blockIdx.x * 8 + (threadIdx.x >> 5);
    const int lane = threadIdx.x & 31;
    if (node >= N) return;
    const float di = dinv[node];

    float acc[8];
    {
        uint4 sv = *(const uint4*)(h + (size_t)node * FDIM + lane * 8);
        const unsigned* u = (const unsigned*)&sv;
#pragma unroll
        for (int i = 0; i < 4; i++) {
            acc[2 * i]     = di * di * __uint_as_float(u[i] << 16);
            acc[2 * i + 1] = di * di * __uint_as_float(u[i] & 0xFFFF0000u);
        }
        float4 b0 = *(const float4*)(bias + lane * 8);
        float4 b1 = *(const float4*)(bias + lane * 8 + 4);
        acc[0] += b0.x; acc[1] += b0.y; acc[2] += b0.z; acc[3] += b0.w;
        acc[4] += b1.x; acc[5] += b1.y; acc[6] += b1.z; acc[7] += b1.w;
    }

    const int beg = rowptr[node];
    const int end = rowptr[node + 1];
    int p = beg;
    for (; p + 4 <= end; p += 4) {
        int s0 = srcs[p], s1 = srcs[p + 1], s2 = srcs[p + 2], s3 = srcs[p + 3];
        float n0 = dinv[s0] * di, n1 = dinv[s1] * di;
        float n2 = dinv[s2] * di, n3 = dinv[s3] * di;
        uint4 v0 = *(const uint4*)(h + (size_t)s0 * FDIM + lane * 8);
        uint4 v1 = *(const uint4*)(h + (size_t)s1 * FDIM + lane * 8);
        uint4 v2 = *(const uint4*)(h + (size_t)s2 * FDIM + lane * 8);
        uint4 v3 = *(const uint4*)(h + (size_t)s3 * FDIM + lane * 8);
        accum8(acc, v0, n0);
        accum8(acc, v1, n1);
        accum8(acc, v2, n2);
        accum8(acc, v3, n3);
    }
    for (; p < end; p++) {
        int s = srcs[p];
        float nm = dinv[s] * di;
        uint4 v = *(const uint4*)(h + (size_t)s * FDIM + lane * 8);
        accum8(acc, v, nm);
    }

    unsigned short o[8];
#pragma unroll
    for (int i = 0; i < 8; i++) o[i] = f2bf(fmaxf(acc[i], 0.0f));
    *(uint4*)(out + (size_t)node * FDIM + lane * 8) = *(uint4*)o;
}

// ---------------- global add pool (bf16 state; batch sorted; run-length atomics) ----------------

__global__ __launch_bounds__(256) void pool_kernel(const unsigned short* __restrict__ state,
                                                   const int* __restrict__ batch,
                                                   float* __restrict__ g, int N) {
    int n0 = blockIdx.x * 16;
    int f = threadIdx.x;
    int cur = -1;
    float run = 0.0f;
    for (int i = 0; i < 16; i++) {
        int n = n0 + i;
        if (n >= N) break;
        int b = batch[n];
        if (b != cur) {
            if (cur >= 0) atomicAdd(&g[(size_t)cur * FDIM + f], run);
            cur = b;
            run = 0.0f;
        }
        run += bf2f(state[(size_t)n * FDIM + f]);
    }
    if (cur >= 0) atomicAdd(&g[(size_t)cur * FDIM + f], run);
}

// ---------------- fused FC head: FC1 + relu + FC2 + log_softmax ----------------

__global__ __launch_bounds__(256) void fc_head_kernel(const float* __restrict__ g,
                                                      const float* __restrict__ fc1W,
                                                      const float* __restrict__ fc1b,
                                                      const float* __restrict__ fc2W,
                                                      const float* __restrict__ fc2b,
                                                      float* __restrict__ out) {
    __shared__ float gs[FDIM];
    __shared__ float hs[FDIM];
    __shared__ float logits[NCLASS];
    const int r = blockIdx.x;
    const int t = threadIdx.x;

    gs[t] = g[(size_t)r * FDIM + t];
    __syncthreads();

    float a1 = fc1b[t];
    for (int k = 0; k < FDIM; k++) a1 += gs[k] * fc1W[(size_t)k * FDIM + t];
    hs[t] = fmaxf(a1, 0.0f);
    __syncthreads();

    if (t < NCLASS) {
        float a2 = fc2b[t];
        for (int k = 0; k < FDIM; k++) a2 += hs[k] * fc2W[(size_t)k * NCLASS + t];
        logits[t] = a2;
    }
    __syncthreads();

    if (t == 0) {
        float mx = logits[0];
        for (int c = 1; c < NCLASS; c++) mx = fmaxf(mx, logits[c]);
        float ssum = 0.0f;
        for (int c = 0; c < NCLASS; c++) ssum += expf(logits[c] - mx);
        float lse = mx + logf(ssum);
        for (int c = 0; c < NCLASS; c++) out[(size_t)r * NCLASS + c] = logits[c] - lse;
    }
}

// ---------------- launcher ----------------

extern "C" void kernel_launch(void* const* d_in, const int* in_sizes, int n_in,
                              void* d_out, int out_size, void* d_ws, size_t ws_size,
                              hipStream_t stream) {
    const float* x     = (const float*)d_in[0];
    const int*   ei    = (const int*)d_in[1];
    const int*   batch = (const int*)d_in[2];
    const float* W0 = (const float*)d_in[3];  const float* b0 = (const float*)d_in[4];
    const float* W1 = (const float*)d_in[5];  const float* b1 = (const float*)d_in[6];
    const float* W2 = (const float*)d_in[7];  const float* b2 = (const float*)d_in[8];
    const float* fc1W = (const float*)d_in[9];  const float* fc1b = (const float*)d_in[10];
    const float* fc2W = (const float*)d_in[11]; const float* fc2b = (const float*)d_in[12];
    float* out = (float*)d_out;

    const int N = in_sizes[0] / FDIM;
    const int E = in_sizes[1] / 2;
    const int* src = ei;
    const int* dst = ei + E;
    const int Mpad = ((N + 63) / 64) * 64;
    const int nb   = (N + 1023) / 1024;       // scan blocks (<=256 supported)

    // workspace layout (16B-aligned chunks)
    char* p = (char*)d_ws;
    unsigned short* S0 = (unsigned short*)p; p += (size_t)Mpad * FDIM * 2;  // node state A
    unsigned short* S1 = (unsigned short*)p; p += (size_t)Mpad * FDIM * 2;  // node state B
    unsigned short* H  = (unsigned short*)p; p += (size_t)Mpad * FDIM * 2;  // GEMM out
    unsigned short* Wp0 = (unsigned short*)p; p += (size_t)8192 * 8 * 2;
    unsigned short* Wp1 = (unsigned short*)p; p += (size_t)8192 * 8 * 2;
    unsigned short* Wp2 = (unsigned short*)p; p += (size_t)8192 * 8 * 2;
    float* dinv = (float*)p; p += (size_t)N * 4;
    int*   cnt  = (int*)p;   p += (size_t)N * 4;        // reused as fill cursor
    int*   rowptr = (int*)p; p += (size_t)(N + 4) * 4;
    int*   bsum = (int*)p;   p += (size_t)256 * 4;
    int*   srcs = (int*)p;   p += (size_t)E * 4;
    float* g    = (float*)p;

    // ---- CSR build (hierarchical scan) ----
    hipMemsetAsync(cnt, 0, (size_t)N * sizeof(int), stream);
    count_kernel<<<(E + 255) / 256, 256, 0, stream>>>(dst, cnt, E);
    csr_bsum<<<nb, 256, 0, stream>>>(cnt, bsum, N);
    csr_bscan<<<1, 256, 0, stream>>>(bsum, nb);
    csr_scan2<<<nb, 256, 0, stream>>>(cnt, bsum, rowptr, dinv, N, E);
    hipMemsetAsync(cnt, 0, (size_t)N * sizeof(int), stream);
    fill_kernel<<<(E + 255) / 256, 256, 0, stream>>>(src, dst, rowptr, cnt, srcs, E);

    // ---- casts / weight packs ----
    cast_kernel<<<((N * FDIM / 4) + 255) / 256, 256, 0, stream>>>((const float4*)x, S0, N * FDIM / 4);
    packw_kernel<<<32, 256, 0, stream>>>(W0, Wp0);
    packw_kernel<<<32, 256, 0, stream>>>(W1, Wp1);
    packw_kernel<<<32, 256, 0, stream>>>(W2, Wp2);

    // ---- 3 GCN layers ----
    const unsigned short* Wps[3] = {Wp0, Wp1, Wp2};
    const float* bs[3] = {b0, b1, b2};
    unsigned short* states[4] = {S0, S1, S0, S1};
    for (int l = 0; l < 3; l++) {
        mfma_gemm<<<(N + 63) / 64, 256, 0, stream>>>(states[l], Wps[l], H, N);
        gather_kernel<<<(N + 7) / 8, 256, 0, stream>>>(H, rowptr, srcs, dinv, bs[l],
                                                       states[l + 1], N);
    }

    // ---- head ----
    hipMemsetAsync(g, 0, (size_t)NGRAPH * FDIM * sizeof(float), stream);
    pool_kernel<<<(N + 15) / 16, 256, 0, stream>>>(states[3], batch, g, N);
    fc_head_kernel<<<NGRAPH, 256, 0, stream>>>(g, fc1W, fc1b, fc2W, fc2b, out);
}

// Round 7
// 524.970 us; speedup vs baseline: 1.3464x; 1.0152x over previous
//
#include <hip/hip_runtime.h>
#include <math.h>

#define FDIM 256
#define NGRAPH 128
#define NCLASS 10

typedef short short8 __attribute__((ext_vector_type(8)));
typedef float floatx4 __attribute__((ext_vector_type(4)));

// fp32 <-> bf16 helpers (RNE)
static __device__ __forceinline__ unsigned short f2bf(float f) {
    unsigned u = __float_as_uint(f);
    u += 0x7FFF + ((u >> 16) & 1);
    return (unsigned short)(u >> 16);
}
static __device__ __forceinline__ float bf2f(unsigned short h) {
    return __uint_as_float(((unsigned)h) << 16);
}

// ---------------- CSR build ----------------

__global__ void count_kernel(const int* __restrict__ dst, int* __restrict__ cnt, int E) {
    int e = blockIdx.x * blockDim.x + threadIdx.x;
    if (e < E) atomicAdd(&cnt[dst[e]], 1);
}

// stage 1: per-block (1024-elem) sums of cnt
__global__ __launch_bounds__(256) void csr_bsum(const int* __restrict__ cnt,
                                                int* __restrict__ bsum, int N) {
    __shared__ int red[256];
    const int t = threadIdx.x;
    const int base = blockIdx.x * 1024 + t * 4;
    int s = 0;
#pragma unroll
    for (int i = 0; i < 4; i++)
        if (base + i < N) s += cnt[base + i];
    red[t] = s;
    __syncthreads();
    for (int off = 128; off > 0; off >>= 1) {
        if (t < off) red[t] += red[t + off];
        __syncthreads();
    }
    if (t == 0) bsum[blockIdx.x] = red[0];
}

// stage 2: exclusive scan of bsum (nb <= 256), in place
__global__ __launch_bounds__(256) void csr_bscan(int* __restrict__ bsum, int nb) {
    __shared__ int s[256];
    const int t = threadIdx.x;
    if (t < nb) s[t] = bsum[t];
    __syncthreads();
    if (t == 0) {
        int run = 0;
        for (int i = 0; i < nb; i++) { int v = s[i]; s[i] = run; run += v; }
    }
    __syncthreads();
    if (t < nb) bsum[t] = s[t];
}

// stage 3: block-local scan + block offset -> rowptr; dinv = rsqrt(cnt+1)
__global__ __launch_bounds__(256) void csr_scan2(const int* __restrict__ cnt,
                                                 const int* __restrict__ boff,
                                                 int* __restrict__ rowptr,
                                                 float* __restrict__ dinv, int N, int E) {
    __shared__ int tsum[256];
    const int t = threadIdx.x;
    const int base = blockIdx.x * 1024 + t * 4;
    int c[4];
    int s = 0;
#pragma unroll
    for (int i = 0; i < 4; i++) {
        c[i] = (base + i < N) ? cnt[base + i] : 0;
        s += c[i];
    }
    tsum[t] = s;
    __syncthreads();
    for (int off = 1; off < 256; off <<= 1) {
        int v = (t >= off) ? tsum[t - off] : 0;
        __syncthreads();
        tsum[t] += v;
        __syncthreads();
    }
    int run = boff[blockIdx.x] + ((t == 0) ? 0 : tsum[t - 1]);
#pragma unroll
    for (int i = 0; i < 4; i++) {
        int idx = base + i;
        if (idx < N) {
            rowptr[idx] = run;
            dinv[idx] = rsqrtf((float)c[i] + 1.0f);   // +1 = self loop
            run += c[i];
        }
    }
    if (blockIdx.x == 0 && t == 0) rowptr[N] = E;
}

__global__ void fill_kernel(const int* __restrict__ src, const int* __restrict__ dst,
                            const int* __restrict__ rowptr, int* __restrict__ cursor,
                            int* __restrict__ srcs, int E) {
    int e = blockIdx.x * blockDim.x + threadIdx.x;
    if (e < E) {
        int d = dst[e];
        int pos = atomicAdd(&cursor[d], 1);
        srcs[rowptr[d] + pos] = src[e];
    }
}

// ---------------- fp32 -> bf16 cast ----------------

__global__ __launch_bounds__(256) void cast_kernel(const float4* __restrict__ in,
                                                   unsigned short* __restrict__ out, int n4) {
    int i = blockIdx.x * blockDim.x + threadIdx.x;
    if (i < n4) {
        float4 v = in[i];
        unsigned short o[4] = {f2bf(v.x), f2bf(v.y), f2bf(v.z), f2bf(v.w)};
        *(uint2*)(out + (size_t)i * 4) = *(uint2*)o;
    }
}

// ---------------- weight pack: fragment-ordered bf16 ----------------
// Bpack[((kstep*16 + ntile)*64 + lane)*8 + j] = W[kstep*32 + (lane>>4)*8 + j][ntile*16 + (lane&15)]

__global__ __launch_bounds__(256) void packw_kernel(const float* __restrict__ W,
                                                    unsigned short* __restrict__ Bp) {
    int idx = blockIdx.x * blockDim.x + threadIdx.x;   // [0, 8192)
    int kstep = idx >> 10;
    int ntile = (idx >> 6) & 15;
    int lane  = idx & 63;
    int col   = ntile * 16 + (lane & 15);
    int krow  = kstep * 32 + (lane >> 4) * 8;
    unsigned short o[8];
#pragma unroll
    for (int j = 0; j < 8; j++) o[j] = f2bf(W[(size_t)(krow + j) * FDIM + col]);
    *(uint4*)(Bp + (size_t)idx * 8) = *(uint4*)o;
}

// ---------------- bf16 MFMA GEMM: C[M,256] = A[M,256] @ W ----------------
// block = 4 waves; wave -> 32 rows (2 m-tiles) x full 256 cols (16 n-tiles).
// 2 m-tiles amortize B-frag loads: per kstep 18 loads / 32 MFMA.

__global__ __launch_bounds__(256, 2) void mfma_gemm(const unsigned short* __restrict__ A,
                                                    const unsigned short* __restrict__ Bp,
                                                    unsigned short* __restrict__ C, int M) {
    const int wave = threadIdx.x >> 6;
    const int lane = threadIdx.x & 63;
    const int quad = lane >> 4;
    const int m    = lane & 15;
    const int row0 = blockIdx.x * 128 + wave * 32;     // rows row0 .. row0+31

    const short* arow0 = (const short*)A + (size_t)(row0 + m) * FDIM + quad * 8;
    const short* arow1 = arow0 + 16 * FDIM;

    floatx4 acc0[16], acc1[16];
#pragma unroll
    for (int i = 0; i < 16; i++) {
        acc0[i] = (floatx4){0.f, 0.f, 0.f, 0.f};
        acc1[i] = (floatx4){0.f, 0.f, 0.f, 0.f};
    }

#pragma unroll
    for (int kstep = 0; kstep < 8; kstep++) {
        short8 a0 = *(const short8*)(arow0 + kstep * 32);
        short8 a1 = *(const short8*)(arow1 + kstep * 32);
#pragma unroll
        for (int nt = 0; nt < 16; nt++) {
            short8 b = *(const short8*)((const short*)Bp +
                         ((size_t)(kstep * 16 + nt) * 64 + lane) * 8);
            acc0[nt] = __builtin_amdgcn_mfma_f32_16x16x32_bf16(a0, b, acc0[nt], 0, 0, 0);
            acc1[nt] = __builtin_amdgcn_mfma_f32_16x16x32_bf16(a1, b, acc1[nt], 0, 0, 0);
        }
    }

    // C/D layout: col = lane&15, row = quad*4 + r
#pragma unroll
    for (int nt = 0; nt < 16; nt++) {
        int col = nt * 16 + m;
#pragma unroll
        for (int r = 0; r < 4; r++) {
            int row = row0 + quad * 4 + r;
            if (row < M)      C[(size_t)row * FDIM + col]        = f2bf(acc0[nt][r]);
            if (row + 16 < M) C[(size_t)(row + 16) * FDIM + col] = f2bf(acc1[nt][r]);
        }
    }
}

// ---------------- fused gather + self-loop + bias + relu (bf16 state) ----------------
// half-wave (32 lanes) per dst node; lane = 8 feats (16B). Edge loop unrolled x8 for MLP.

static __device__ __forceinline__ void accum8(float* acc, uint4 v, float nm) {
    const unsigned* u = (const unsigned*)&v;
#pragma unroll
    for (int i = 0; i < 4; i++) {
        acc[2 * i]     += nm * __uint_as_float(u[i] << 16);
        acc[2 * i + 1] += nm * __uint_as_float(u[i] & 0xFFFF0000u);
    }
}

__global__ __launch_bounds__(256) void gather_kernel(const unsigned short* __restrict__ h,
                                                     const int* __restrict__ rowptr,
                                                     const int* __restrict__ srcs,
                                                     const float* __restrict__ dinv,
                                                     const float* __restrict__ bias,
                                                     unsigned short* __restrict__ out, int N) {
    const int node = blockIdx.x * 8 + (threadIdx.x >> 5);
    const int lane = threadIdx.x & 31;
    if (node >= N) return;
    const float di = dinv[node];

    float acc[8];
    {
        uint4 sv = *(const uint4*)(h + (size_t)node * FDIM + lane * 8);
        const unsigned* u = (const unsigned*)&sv;
#pragma unroll
        for (int i = 0; i < 4; i++) {
            acc[2 * i]     = di * di * __uint_as_float(u[i] << 16);
            acc[2 * i + 1] = di * di * __uint_as_float(u[i] & 0xFFFF0000u);
        }
        float4 b0 = *(const float4*)(bias + lane * 8);
        float4 b1 = *(const float4*)(bias + lane * 8 + 4);
        acc[0] += b0.x; acc[1] += b0.y; acc[2] += b0.z; acc[3] += b0.w;
        acc[4] += b1.x; acc[5] += b1.y; acc[6] += b1.z; acc[7] += b1.w;
    }

    const int beg = rowptr[node];
    const int end = rowptr[node + 1];
    int p = beg;
    for (; p + 8 <= end; p += 8) {
        int s0 = srcs[p],     s1 = srcs[p + 1], s2 = srcs[p + 2], s3 = srcs[p + 3];
        int s4 = srcs[p + 4], s5 = srcs[p + 5], s6 = srcs[p + 6], s7 = srcs[p + 7];
        float n0 = dinv[s0] * di, n1 = dinv[s1] * di, n2 = dinv[s2] * di, n3 = dinv[s3] * di;
        float n4 = dinv[s4] * di, n5 = dinv[s5] * di, n6 = dinv[s6] * di, n7 = dinv[s7] * di;
        uint4 v0 = *(const uint4*)(h + (size_t)s0 * FDIM + lane * 8);
        uint4 v1 = *(const uint4*)(h + (size_t)s1 * FDIM + lane * 8);
        uint4 v2 = *(const uint4*)(h + (size_t)s2 * FDIM + lane * 8);
        uint4 v3 = *(const uint4*)(h + (size_t)s3 * FDIM + lane * 8);
        uint4 v4 = *(const uint4*)(h + (size_t)s4 * FDIM + lane * 8);
        uint4 v5 = *(const uint4*)(h + (size_t)s5 * FDIM + lane * 8);
        uint4 v6 = *(const uint4*)(h + (size_t)s6 * FDIM + lane * 8);
        uint4 v7 = *(const uint4*)(h + (size_t)s7 * FDIM + lane * 8);
        accum8(acc, v0, n0); accum8(acc, v1, n1); accum8(acc, v2, n2); accum8(acc, v3, n3);
        accum8(acc, v4, n4); accum8(acc, v5, n5); accum8(acc, v6, n6); accum8(acc, v7, n7);
    }
    for (; p + 4 <= end; p += 4) {
        int s0 = srcs[p], s1 = srcs[p + 1], s2 = srcs[p + 2], s3 = srcs[p + 3];
        float n0 = dinv[s0] * di, n1 = dinv[s1] * di;
        float n2 = dinv[s2] * di, n3 = dinv[s3] * di;
        uint4 v0 = *(const uint4*)(h + (size_t)s0 * FDIM + lane * 8);
        uint4 v1 = *(const uint4*)(h + (size_t)s1 * FDIM + lane * 8);
        uint4 v2 = *(const uint4*)(h + (size_t)s2 * FDIM + lane * 8);
        uint4 v3 = *(const uint4*)(h + (size_t)s3 * FDIM + lane * 8);
        accum8(acc, v0, n0); accum8(acc, v1, n1); accum8(acc, v2, n2); accum8(acc, v3, n3);
    }
    for (; p < end; p++) {
        int s = srcs[p];
        float nm = dinv[s] * di;
        uint4 v = *(const uint4*)(h + (size_t)s * FDIM + lane * 8);
        accum8(acc, v, nm);
    }

    unsigned short o[8];
#pragma unroll
    for (int i = 0; i < 8; i++) o[i] = f2bf(fmaxf(acc[i], 0.0f));
    *(uint4*)(out + (size_t)node * FDIM + lane * 8) = *(uint4*)o;
}

// ---------------- global add pool (bf16 state; batch sorted; run-length atomics) ----------------

__global__ __launch_bounds__(256) void pool_kernel(const unsigned short* __restrict__ state,
                                                   const int* __restrict__ batch,
                                                   float* __restrict__ g, int N) {
    int n0 = blockIdx.x * 16;
    int f = threadIdx.x;
    int cur = -1;
    float run = 0.0f;
    for (int i = 0; i < 16; i++) {
        int n = n0 + i;
        if (n >= N) break;
        int b = batch[n];
        if (b != cur) {
            if (cur >= 0) atomicAdd(&g[(size_t)cur * FDIM + f], run);
            cur = b;
            run = 0.0f;
        }
        run += bf2f(state[(size_t)n * FDIM + f]);
    }
    if (cur >= 0) atomicAdd(&g[(size_t)cur * FDIM + f], run);
}

// ---------------- fused FC head: FC1 + relu + FC2 + log_softmax ----------------

__global__ __launch_bounds__(256) void fc_head_kernel(const float* __restrict__ g,
                                                      const float* __restrict__ fc1W,
                                                      const float* __restrict__ fc1b,
                                                      const float* __restrict__ fc2W,
                                                      const float* __restrict__ fc2b,
                                                      float* __restrict__ out) {
    __shared__ float gs[FDIM];
    __shared__ float hs[FDIM];
    __shared__ float logits[NCLASS];
    const int r = blockIdx.x;
    const int t = threadIdx.x;

    gs[t] = g[(size_t)r * FDIM + t];
    __syncthreads();

    float a1 = fc1b[t];
    for (int k = 0; k < FDIM; k++) a1 += gs[k] * fc1W[(size_t)k * FDIM + t];
    hs[t] = fmaxf(a1, 0.0f);
    __syncthreads();

    if (t < NCLASS) {
        float a2 = fc2b[t];
        for (int k = 0; k < FDIM; k++) a2 += hs[k] * fc2W[(size_t)k * NCLASS + t];
        logits[t] = a2;
    }
    __syncthreads();

    if (t == 0) {
        float mx = logits[0];
        for (int c = 1; c < NCLASS; c++) mx = fmaxf(mx, logits[c]);
        float ssum = 0.0f;
        for (int c = 0; c < NCLASS; c++) ssum += expf(logits[c] - mx);
        float lse = mx + logf(ssum);
        for (int c = 0; c < NCLASS; c++) out[(size_t)r * NCLASS + c] = logits[c] - lse;
    }
}

// ---------------- launcher ----------------

extern "C" void kernel_launch(void* const* d_in, const int* in_sizes, int n_in,
                              void* d_out, int out_size, void* d_ws, size_t ws_size,
                              hipStream_t stream) {
    const float* x     = (const float*)d_in[0];
    const int*   ei    = (const int*)d_in[1];
    const int*   batch = (const int*)d_in[2];
    const float* W0 = (const float*)d_in[3];  const float* b0 = (const float*)d_in[4];
    const float* W1 = (const float*)d_in[5];  const float* b1 = (const float*)d_in[6];
    const float* W2 = (const float*)d_in[7];  const float* b2 = (const float*)d_in[8];
    const float* fc1W = (const float*)d_in[9];  const float* fc1b = (const float*)d_in[10];
    const float* fc2W = (const float*)d_in[11]; const float* fc2b = (const float*)d_in[12];
    float* out = (float*)d_out;

    const int N = in_sizes[0] / FDIM;
    const int E = in_sizes[1] / 2;
    const int* src = ei;
    const int* dst = ei + E;
    const int Mpad = ((N + 127) / 128) * 128;   // GEMM tiles span 128 rows/block
    const int nb   = (N + 1023) / 1024;         // scan blocks (<=256 supported)

    // workspace layout (16B-aligned chunks)
    char* p = (char*)d_ws;
    unsigned short* S0 = (unsigned short*)p; p += (size_t)Mpad * FDIM * 2;  // node state A
    unsigned short* S1 = (unsigned short*)p; p += (size_t)Mpad * FDIM * 2;  // node state B
    unsigned short* H  = (unsigned short*)p; p += (size_t)Mpad * FDIM * 2;  // GEMM out
    unsigned short* Wp0 = (unsigned short*)p; p += (size_t)8192 * 8 * 2;
    unsigned short* Wp1 = (unsigned short*)p; p += (size_t)8192 * 8 * 2;
    unsigned short* Wp2 = (unsigned short*)p; p += (size_t)8192 * 8 * 2;
    float* dinv = (float*)p; p += (size_t)N * 4;
    int*   cnt  = (int*)p;   p += (size_t)N * 4;        // reused as fill cursor
    int*   rowptr = (int*)p; p += (size_t)(N + 4) * 4;
    int*   bsum = (int*)p;   p += (size_t)256 * 4;
    int*   srcs = (int*)p;   p += (size_t)E * 4;
    float* g    = (float*)p;

    // ---- CSR build (hierarchical scan) ----
    hipMemsetAsync(cnt, 0, (size_t)N * sizeof(int), stream);
    count_kernel<<<(E + 255) / 256, 256, 0, stream>>>(dst, cnt, E);
    csr_bsum<<<nb, 256, 0, stream>>>(cnt, bsum, N);
    csr_bscan<<<1, 256, 0, stream>>>(bsum, nb);
    csr_scan2<<<nb, 256, 0, stream>>>(cnt, bsum, rowptr, dinv, N, E);
    hipMemsetAsync(cnt, 0, (size_t)N * sizeof(int), stream);
    fill_kernel<<<(E + 255) / 256, 256, 0, stream>>>(src, dst, rowptr, cnt, srcs, E);

    // ---- casts / weight packs ----
    cast_kernel<<<((N * FDIM / 4) + 255) / 256, 256, 0, stream>>>((const float4*)x, S0, N * FDIM / 4);
    packw_kernel<<<32, 256, 0, stream>>>(W0, Wp0);
    packw_kernel<<<32, 256, 0, stream>>>(W1, Wp1);
    packw_kernel<<<32, 256, 0, stream>>>(W2, Wp2);

    // ---- 3 GCN layers ----
    const unsigned short* Wps[3] = {Wp0, Wp1, Wp2};
    const float* bs[3] = {b0, b1, b2};
    unsigned short* states[4] = {S0, S1, S0, S1};
    for (int l = 0; l < 3; l++) {
        mfma_gemm<<<(N + 127) / 128, 256, 0, stream>>>(states[l], Wps[l], H, N);
        gather_kernel<<<(N + 7) / 8, 256, 0, stream>>>(H, rowptr, srcs, dinv, bs[l],
                                                       states[l + 1], N);
    }

    // ---- head ----
    hipMemsetAsync(g, 0, (size_t)NGRAPH * FDIM * sizeof(float), stream);
    pool_kernel<<<(N + 15) / 16, 256, 0, stream>>>(states[3], batch, g, N);
    fc_head_kernel<<<NGRAPH, 256, 0, stream>>>(g, fc1W, fc1b, fc2W, fc2b, out);
}

// Round 8
// 479.301 us; speedup vs baseline: 1.4746x; 1.0953x over previous
//
#include <hip/hip_runtime.h>
#include <math.h>

#define FDIM 256
#define NGRAPH 128
#define NCLASS 10

typedef short short8 __attribute__((ext_vector_type(8)));
typedef float floatx4 __attribute__((ext_vector_type(4)));

// fp32 <-> bf16 helpers (RNE)
static __device__ __forceinline__ unsigned short f2bf(float f) {
    unsigned u = __float_as_uint(f);
    u += 0x7FFF + ((u >> 16) & 1);
    return (unsigned short)(u >> 16);
}
static __device__ __forceinline__ float bf2f(unsigned short h) {
    return __uint_as_float(((unsigned)h) << 16);
}

// ---------------- CSR build ----------------
// count + slot in one pass: slot[e] = running index of edge e within its dst bucket.

__global__ void count_slot_kernel(const int* __restrict__ dst, int* __restrict__ cnt,
                                  int* __restrict__ slot, int E) {
    int e = blockIdx.x * blockDim.x + threadIdx.x;
    if (e < E) slot[e] = atomicAdd(&cnt[dst[e]], 1);
}

// stage 1: per-block (1024-elem) sums of cnt
__global__ __launch_bounds__(256) void csr_bsum(const int* __restrict__ cnt,
                                                int* __restrict__ bsum, int N) {
    __shared__ int red[256];
    const int t = threadIdx.x;
    const int base = blockIdx.x * 1024 + t * 4;
    int s = 0;
#pragma unroll
    for (int i = 0; i < 4; i++)
        if (base + i < N) s += cnt[base + i];
    red[t] = s;
    __syncthreads();
    for (int off = 128; off > 0; off >>= 1) {
        if (t < off) red[t] += red[t + off];
        __syncthreads();
    }
    if (t == 0) bsum[blockIdx.x] = red[0];
}

// stage 2: exclusive scan of bsum (nb <= 256), in place
__global__ __launch_bounds__(256) void csr_bscan(int* __restrict__ bsum, int nb) {
    __shared__ int s[256];
    const int t = threadIdx.x;
    if (t < nb) s[t] = bsum[t];
    __syncthreads();
    if (t == 0) {
        int run = 0;
        for (int i = 0; i < nb; i++) { int v = s[i]; s[i] = run; run += v; }
    }
    __syncthreads();
    if (t < nb) bsum[t] = s[t];
}

// stage 3: block-local scan + block offset -> rowptr; dinv = rsqrt(cnt+1)
__global__ __launch_bounds__(256) void csr_scan2(const int* __restrict__ cnt,
                                                 const int* __restrict__ boff,
                                                 int* __restrict__ rowptr,
                                                 float* __restrict__ dinv, int N, int E) {
    __shared__ int tsum[256];
    const int t = threadIdx.x;
    const int base = blockIdx.x * 1024 + t * 4;
    int c[4];
    int s = 0;
#pragma unroll
    for (int i = 0; i < 4; i++) {
        c[i] = (base + i < N) ? cnt[base + i] : 0;
        s += c[i];
    }
    tsum[t] = s;
    __syncthreads();
    for (int off = 1; off < 256; off <<= 1) {
        int v = (t >= off) ? tsum[t - off] : 0;
        __syncthreads();
        tsum[t] += v;
        __syncthreads();
    }
    int run = boff[blockIdx.x] + ((t == 0) ? 0 : tsum[t - 1]);
#pragma unroll
    for (int i = 0; i < 4; i++) {
        int idx = base + i;
        if (idx < N) {
            rowptr[idx] = run;
            dinv[idx] = rsqrtf((float)c[i] + 1.0f);   // +1 = self loop
            run += c[i];
        }
    }
    if (blockIdx.x == 0 && t == 0) rowptr[N] = E;
}

// fill: no atomics — slot[] already assigned during count
__global__ void fill_kernel(const int* __restrict__ src, const int* __restrict__ dst,
                            const int* __restrict__ rowptr, const int* __restrict__ slot,
                            int* __restrict__ srcs, int E) {
    int e = blockIdx.x * blockDim.x + threadIdx.x;
    if (e < E) srcs[rowptr[dst[e]] + slot[e]] = src[e];
}

// ---------------- fp32 -> bf16 cast ----------------

__global__ __launch_bounds__(256) void cast_kernel(const float4* __restrict__ in,
                                                   unsigned short* __restrict__ out, int n4) {
    int i = blockIdx.x * blockDim.x + threadIdx.x;
    if (i < n4) {
        float4 v = in[i];
        unsigned short o[4] = {f2bf(v.x), f2bf(v.y), f2bf(v.z), f2bf(v.w)};
        *(uint2*)(out + (size_t)i * 4) = *(uint2*)o;
    }
}

// ---------------- weight pack (all 3) + zero g, one dispatch ----------------
// blocks 0..95: pack W0/W1/W2 into fragment order; blocks 96..127: zero g (128KB).
// Bpack[((kstep*16 + ntile)*64 + lane)*8 + j] = W[kstep*32 + (lane>>4)*8 + j][ntile*16 + (lane&15)]

__global__ __launch_bounds__(256) void packw_all_kernel(const float* __restrict__ W0,
                                                        const float* __restrict__ W1,
                                                        const float* __restrict__ W2,
                                                        unsigned short* __restrict__ Bp0,
                                                        unsigned short* __restrict__ Bp1,
                                                        unsigned short* __restrict__ Bp2,
                                                        float4* __restrict__ g4) {
    const int b = blockIdx.x;
    if (b >= 96) {
        // zero g: 32 blocks x 256 threads x 1 float4 = 32768 floats
        g4[(size_t)(b - 96) * 256 + threadIdx.x] = (float4){0.f, 0.f, 0.f, 0.f};
        return;
    }
    const float* W = (b < 32) ? W0 : (b < 64) ? W1 : W2;
    unsigned short* Bp = (b < 32) ? Bp0 : (b < 64) ? Bp1 : Bp2;
    int idx = (b & 31) * 256 + threadIdx.x;   // [0, 8192)
    int kstep = idx >> 10;
    int ntile = (idx >> 6) & 15;
    int lane  = idx & 63;
    int col   = ntile * 16 + (lane & 15);
    int krow  = kstep * 32 + (lane >> 4) * 8;
    unsigned short o[8];
#pragma unroll
    for (int j = 0; j < 8; j++) o[j] = f2bf(W[(size_t)(krow + j) * FDIM + col]);
    *(uint4*)(Bp + (size_t)idx * 8) = *(uint4*)o;
}

// ---------------- bf16 MFMA GEMM: C[M,256] = A[M,256] @ W ----------------
// block = 4 waves; wave -> 32 rows (2 m-tiles) x full 256 cols (16 n-tiles).

__global__ __launch_bounds__(256, 2) void mfma_gemm(const unsigned short* __restrict__ A,
                                                    const unsigned short* __restrict__ Bp,
                                                    unsigned short* __restrict__ C, int M) {
    const int wave = threadIdx.x >> 6;
    const int lane = threadIdx.x & 63;
    const int quad = lane >> 4;
    const int m    = lane & 15;
    const int row0 = blockIdx.x * 128 + wave * 32;

    const short* arow0 = (const short*)A + (size_t)(row0 + m) * FDIM + quad * 8;
    const short* arow1 = arow0 + 16 * FDIM;

    floatx4 acc0[16], acc1[16];
#pragma unroll
    for (int i = 0; i < 16; i++) {
        acc0[i] = (floatx4){0.f, 0.f, 0.f, 0.f};
        acc1[i] = (floatx4){0.f, 0.f, 0.f, 0.f};
    }

#pragma unroll
    for (int kstep = 0; kstep < 8; kstep++) {
        short8 a0 = *(const short8*)(arow0 + kstep * 32);
        short8 a1 = *(const short8*)(arow1 + kstep * 32);
#pragma unroll
        for (int nt = 0; nt < 16; nt++) {
            short8 b = *(const short8*)((const short*)Bp +
                         ((size_t)(kstep * 16 + nt) * 64 + lane) * 8);
            acc0[nt] = __builtin_amdgcn_mfma_f32_16x16x32_bf16(a0, b, acc0[nt], 0, 0, 0);
            acc1[nt] = __builtin_amdgcn_mfma_f32_16x16x32_bf16(a1, b, acc1[nt], 0, 0, 0);
        }
    }

    // C/D layout: col = lane&15, row = quad*4 + r
#pragma unroll
    for (int nt = 0; nt < 16; nt++) {
        int col = nt * 16 + m;
#pragma unroll
        for (int r = 0; r < 4; r++) {
            int row = row0 + quad * 4 + r;
            if (row < M)      C[(size_t)row * FDIM + col]        = f2bf(acc0[nt][r]);
            if (row + 16 < M) C[(size_t)(row + 16) * FDIM + col] = f2bf(acc1[nt][r]);
        }
    }
}

// ---------------- fused gather + self-loop + bias + relu (bf16 state) ----------------
// half-wave (32 lanes) per dst node; lane = 8 feats (16B). Edge loop unrolled x4.

static __device__ __forceinline__ void accum8(float* acc, uint4 v, float nm) {
    const unsigned* u = (const unsigned*)&v;
#pragma unroll
    for (int i = 0; i < 4; i++) {
        acc[2 * i]     += nm * __uint_as_float(u[i] << 16);
        acc[2 * i + 1] += nm * __uint_as_float(u[i] & 0xFFFF0000u);
    }
}

__global__ __launch_bounds__(256) void gather_kernel(const unsigned short* __restrict__ h,
                                                     const int* __restrict__ rowptr,
                                                     const int* __restrict__ srcs,
                                                     const float* __restrict__ dinv,
                                                     const float* __restrict__ bias,
                                                     unsigned short* __restrict__ out, int N) {
    const int node = blockIdx.x * 8 + (threadIdx.x >> 5);
    const int lane = threadIdx.x & 31;
    if (node >= N) return;
    const float di = dinv[node];

    float acc[8];
    {
        uint4 sv = *(const uint4*)(h + (size_t)node * FDIM + lane * 8);
        const unsigned* u = (const unsigned*)&sv;
#pragma unroll
        for (int i = 0; i < 4; i++) {
            acc[2 * i]     = di * di * __uint_as_float(u[i] << 16);
            acc[2 * i + 1] = di * di * __uint_as_float(u[i] & 0xFFFF0000u);
        }
        float4 b0 = *(const float4*)(bias + lane * 8);
        float4 b1 = *(const float4*)(bias + lane * 8 + 4);
        acc[0] += b0.x; acc[1] += b0.y; acc[2] += b0.z; acc[3] += b0.w;
        acc[4] += b1.x; acc[5] += b1.y; acc[6] += b1.z; acc[7] += b1.w;
    }

    const int beg = rowptr[node];
    const int end = rowptr[node + 1];
    int p = beg;
    for (; p + 4 <= end; p += 4) {
        int s0 = srcs[p], s1 = srcs[p + 1], s2 = srcs[p + 2], s3 = srcs[p + 3];
        float n0 = dinv[s0] * di, n1 = dinv[s1] * di;
        float n2 = dinv[s2] * di, n3 = dinv[s3] * di;
        uint4 v0 = *(const uint4*)(h + (size_t)s0 * FDIM + lane * 8);
        uint4 v1 = *(const uint4*)(h + (size_t)s1 * FDIM + lane * 8);
        uint4 v2 = *(const uint4*)(h + (size_t)s2 * FDIM + lane * 8);
        uint4 v3 = *(const uint4*)(h + (size_t)s3 * FDIM + lane * 8);
        accum8(acc, v0, n0);
        accum8(acc, v1, n1);
        accum8(acc, v2, n2);
        accum8(acc, v3, n3);
    }
    for (; p < end; p++) {
        int s = srcs[p];
        float nm = dinv[s] * di;
        uint4 v = *(const uint4*)(h + (size_t)s * FDIM + lane * 8);
        accum8(acc, v, nm);
    }

    unsigned short o[8];
#pragma unroll
    for (int i = 0; i < 8; i++) o[i] = f2bf(fmaxf(acc[i], 0.0f));
    *(uint4*)(out + (size_t)node * FDIM + lane * 8) = *(uint4*)o;
}

// ---------------- global add pool (bf16 state; batch sorted; run-length atomics) ----------------

__global__ __launch_bounds__(256) void pool_kernel(const unsigned short* __restrict__ state,
                                                   const int* __restrict__ batch,
                                                   float* __restrict__ g, int N) {
    int n0 = blockIdx.x * 16;
    int f = threadIdx.x;
    int cur = -1;
    float run = 0.0f;
    for (int i = 0; i < 16; i++) {
        int n = n0 + i;
        if (n >= N) break;
        int b = batch[n];
        if (b != cur) {
            if (cur >= 0) atomicAdd(&g[(size_t)cur * FDIM + f], run);
            cur = b;
            run = 0.0f;
        }
        run += bf2f(state[(size_t)n * FDIM + f]);
    }
    if (cur >= 0) atomicAdd(&g[(size_t)cur * FDIM + f], run);
}

// ---------------- fused FC head: FC1 + relu + FC2 + log_softmax ----------------
// k-dim split across 4 waves (fc1) / 16 segments (fc2) to cut serial chains.

__global__ __launch_bounds__(256) void fc_head_kernel(const float* __restrict__ g,
                                                      const float* __restrict__ fc1W,
                                                      const float* __restrict__ fc1b,
                                                      const float* __restrict__ fc2W,
                                                      const float* __restrict__ fc2b,
                                                      float* __restrict__ out) {
    __shared__ float gs[FDIM];
    __shared__ float part[4][FDIM];
    __shared__ float hs[FDIM];
    __shared__ float p2[256];
    __shared__ float logits[NCLASS];
    const int r = blockIdx.x;
    const int t = threadIdx.x;
    const int w = t >> 6;       // wave
    const int l = t & 63;       // lane

    gs[t] = g[(size_t)r * FDIM + t];
    __syncthreads();

    // fc1: wave w covers k in [w*64, w*64+64); thread handles 4 cols (l, l+64, l+128, l+192)
    float a[4] = {0.f, 0.f, 0.f, 0.f};
    for (int kk = 0; kk < 64; kk++) {
        int k = w * 64 + kk;
        float gv = gs[k];
#pragma unroll
        for (int j = 0; j < 4; j++) a[j] += gv * fc1W[(size_t)k * FDIM + j * 64 + l];
    }
#pragma unroll
    for (int j = 0; j < 4; j++) part[w][j * 64 + l] = a[j];
    __syncthreads();

    float s1 = part[0][t] + part[1][t] + part[2][t] + part[3][t] + fc1b[t];
    hs[t] = fmaxf(s1, 0.0f);
    __syncthreads();

    // fc2: thread t -> class c = t&15 (c<10), k-segment (t>>4)*16..+16
    float a2 = 0.0f;
    const int c = t & 15;
    if (c < NCLASS) {
        int k0 = (t >> 4) * 16;
        for (int kk = 0; kk < 16; kk++)
            a2 += hs[k0 + kk] * fc2W[(size_t)(k0 + kk) * NCLASS + c];
    }
    p2[t] = a2;
    __syncthreads();

    if (t < NCLASS) {
        float s2 = fc2b[t];
        for (int seg = 0; seg < 16; seg++) s2 += p2[seg * 16 + t];
        logits[t] = s2;
    }
    __syncthreads();

    if (t == 0) {
        float mx = logits[0];
        for (int cc = 1; cc < NCLASS; cc++) mx = fmaxf(mx, logits[cc]);
        float ssum = 0.0f;
        for (int cc = 0; cc < NCLASS; cc++) ssum += expf(logits[cc] - mx);
        float lse = mx + logf(ssum);
        for (int cc = 0; cc < NCLASS; cc++) out[(size_t)r * NCLASS + cc] = logits[cc] - lse;
    }
}

// ---------------- launcher ----------------

extern "C" void kernel_launch(void* const* d_in, const int* in_sizes, int n_in,
                              void* d_out, int out_size, void* d_ws, size_t ws_size,
                              hipStream_t stream) {
    const float* x     = (const float*)d_in[0];
    const int*   ei    = (const int*)d_in[1];
    const int*   batch = (const int*)d_in[2];
    const float* W0 = (const float*)d_in[3];  const float* b0 = (const float*)d_in[4];
    const float* W1 = (const float*)d_in[5];  const float* b1 = (const float*)d_in[6];
    const float* W2 = (const float*)d_in[7];  const float* b2 = (const float*)d_in[8];
    const float* fc1W = (const float*)d_in[9];  const float* fc1b = (const float*)d_in[10];
    const float* fc2W = (const float*)d_in[11]; const float* fc2b = (const float*)d_in[12];
    float* out = (float*)d_out;

    const int N = in_sizes[0] / FDIM;
    const int E = in_sizes[1] / 2;
    const int* src = ei;
    const int* dst = ei + E;
    const int Mpad = ((N + 127) / 128) * 128;   // GEMM tiles span 128 rows/block
    const int nb   = (N + 1023) / 1024;         // scan blocks (<=256 supported)

    // workspace layout (16B-aligned chunks)
    char* p = (char*)d_ws;
    unsigned short* S0 = (unsigned short*)p; p += (size_t)Mpad * FDIM * 2;  // node state A
    unsigned short* S1 = (unsigned short*)p; p += (size_t)Mpad * FDIM * 2;  // node state B
    unsigned short* H  = (unsigned short*)p; p += (size_t)Mpad * FDIM * 2;  // GEMM out
    unsigned short* Wp0 = (unsigned short*)p; p += (size_t)8192 * 8 * 2;
    unsigned short* Wp1 = (unsigned short*)p; p += (size_t)8192 * 8 * 2;
    unsigned short* Wp2 = (unsigned short*)p; p += (size_t)8192 * 8 * 2;
    float* dinv = (float*)p; p += (size_t)N * 4;
    int*   cnt  = (int*)p;   p += (size_t)N * 4;
    int*   rowptr = (int*)p; p += (size_t)(N + 4) * 4;
    int*   bsum = (int*)p;   p += (size_t)256 * 4;
    int*   srcs = (int*)p;   p += (size_t)E * 4;
    int*   slot = (int*)p;   p += (size_t)E * 4;
    float* g    = (float*)p;

    // ---- CSR build ----
    hipMemsetAsync(cnt, 0, (size_t)N * sizeof(int), stream);
    count_slot_kernel<<<(E + 255) / 256, 256, 0, stream>>>(dst, cnt, slot, E);
    csr_bsum<<<nb, 256, 0, stream>>>(cnt, bsum, N);
    csr_bscan<<<1, 256, 0, stream>>>(bsum, nb);
    csr_scan2<<<nb, 256, 0, stream>>>(cnt, bsum, rowptr, dinv, N, E);
    fill_kernel<<<(E + 255) / 256, 256, 0, stream>>>(src, dst, rowptr, slot, srcs, E);

    // ---- cast / weight packs (+ zero g) ----
    cast_kernel<<<((N * FDIM / 4) + 255) / 256, 256, 0, stream>>>((const float4*)x, S0, N * FDIM / 4);
    packw_all_kernel<<<128, 256, 0, stream>>>(W0, W1, W2, Wp0, Wp1, Wp2, (float4*)g);

    // ---- 3 GCN layers ----
    const unsigned short* Wps[3] = {Wp0, Wp1, Wp2};
    const float* bs[3] = {b0, b1, b2};
    unsigned short* states[4] = {S0, S1, S0, S1};
    for (int l = 0; l < 3; l++) {
        mfma_gemm<<<(N + 127) / 128, 256, 0, stream>>>(states[l], Wps[l], H, N);
        gather_kernel<<<(N + 7) / 8, 256, 0, stream>>>(H, rowptr, srcs, dinv, bs[l],
                                                       states[l + 1], N);
    }

    // ---- head ----
    pool_kernel<<<(N + 15) / 16, 256, 0, stream>>>(states[3], batch, g, N);
    fc_head_kernel<<<NGRAPH, 256, 0, stream>>>(g, fc1W, fc1b, fc2W, fc2b, out);
}

// Round 9
// 450.501 us; speedup vs baseline: 1.5689x; 1.0639x over previous
//
#include <hip/hip_runtime.h>
#include <math.h>

#define FDIM 256
#define NGRAPH 128
#define NCLASS 10

typedef short short8 __attribute__((ext_vector_type(8)));
typedef float floatx4 __attribute__((ext_vector_type(4)));

// fp32 <-> bf16 helpers (RNE)
static __device__ __forceinline__ unsigned short f2bf(float f) {
    unsigned u = __float_as_uint(f);
    u += 0x7FFF + ((u >> 16) & 1);
    return (unsigned short)(u >> 16);
}
static __device__ __forceinline__ float bf2f(unsigned short h) {
    return __uint_as_float(((unsigned)h) << 16);
}

// ---------------- prep: count+slot | packw x3 | zero g (one dispatch) ----------------
// blocks [0, nCnt): count_slot; [nCnt, nCnt+96): weight pack; [nCnt+96, nCnt+128): zero g.
// Bpack[((kstep*16 + ntile)*64 + lane)*8 + j] = W[kstep*32 + (lane>>4)*8 + j][ntile*16 + (lane&15)]

__global__ __launch_bounds__(256) void prep_kernel(const int* __restrict__ dst,
                                                   int* __restrict__ cnt,
                                                   int* __restrict__ slot, int E, int nCnt,
                                                   const float* __restrict__ W0,
                                                   const float* __restrict__ W1,
                                                   const float* __restrict__ W2,
                                                   unsigned short* __restrict__ Bp0,
                                                   unsigned short* __restrict__ Bp1,
                                                   unsigned short* __restrict__ Bp2,
                                                   float4* __restrict__ g4) {
    const int b = blockIdx.x;
    const int t = threadIdx.x;
    if (b < nCnt) {
        int e = b * 256 + t;
        if (e < E) slot[e] = atomicAdd(&cnt[dst[e]], 1);
        return;
    }
    const int b2 = b - nCnt;
    if (b2 >= 96) {
        g4[(size_t)(b2 - 96) * 256 + t] = (float4){0.f, 0.f, 0.f, 0.f};
        return;
    }
    const float* W = (b2 < 32) ? W0 : (b2 < 64) ? W1 : W2;
    unsigned short* Bp = (b2 < 32) ? Bp0 : (b2 < 64) ? Bp1 : Bp2;
    int idx = (b2 & 31) * 256 + t;   // [0, 8192)
    int kstep = idx >> 10;
    int ntile = (idx >> 6) & 15;
    int lane  = idx & 63;
    int col   = ntile * 16 + (lane & 15);
    int krow  = kstep * 32 + (lane >> 4) * 8;
    unsigned short o[8];
#pragma unroll
    for (int j = 0; j < 8; j++) o[j] = f2bf(W[(size_t)(krow + j) * FDIM + col]);
    *(uint4*)(Bp + (size_t)idx * 8) = *(uint4*)o;
}

// ---------------- CSR scan stages ----------------

__global__ __launch_bounds__(256) void csr_bsum(const int* __restrict__ cnt,
                                                int* __restrict__ bsum, int N) {
    __shared__ int red[256];
    const int t = threadIdx.x;
    const int base = blockIdx.x * 1024 + t * 4;
    int s = 0;
#pragma unroll
    for (int i = 0; i < 4; i++)
        if (base + i < N) s += cnt[base + i];
    red[t] = s;
    __syncthreads();
    for (int off = 128; off > 0; off >>= 1) {
        if (t < off) red[t] += red[t + off];
        __syncthreads();
    }
    if (t == 0) bsum[blockIdx.x] = red[0];
}

__global__ __launch_bounds__(256) void csr_bscan(int* __restrict__ bsum, int nb) {
    __shared__ int s[256];
    const int t = threadIdx.x;
    if (t < nb) s[t] = bsum[t];
    __syncthreads();
    if (t == 0) {
        int run = 0;
        for (int i = 0; i < nb; i++) { int v = s[i]; s[i] = run; run += v; }
    }
    __syncthreads();
    if (t < nb) bsum[t] = s[t];
}

__global__ __launch_bounds__(256) void csr_scan2(const int* __restrict__ cnt,
                                                 const int* __restrict__ boff,
                                                 int* __restrict__ rowptr,
                                                 float* __restrict__ dinv, int N, int E) {
    __shared__ int tsum[256];
    const int t = threadIdx.x;
    const int base = blockIdx.x * 1024 + t * 4;
    int c[4];
    int s = 0;
#pragma unroll
    for (int i = 0; i < 4; i++) {
        c[i] = (base + i < N) ? cnt[base + i] : 0;
        s += c[i];
    }
    tsum[t] = s;
    __syncthreads();
    for (int off = 1; off < 256; off <<= 1) {
        int v = (t >= off) ? tsum[t - off] : 0;
        __syncthreads();
        tsum[t] += v;
        __syncthreads();
    }
    int run = boff[blockIdx.x] + ((t == 0) ? 0 : tsum[t - 1]);
#pragma unroll
    for (int i = 0; i < 4; i++) {
        int idx = base + i;
        if (idx < N) {
            rowptr[idx] = run;
            dinv[idx] = rsqrtf((float)c[i] + 1.0f);   // +1 = self loop
            run += c[i];
        }
    }
    if (blockIdx.x == 0 && t == 0) rowptr[N] = E;
}

__global__ void fill_kernel(const int* __restrict__ src, const int* __restrict__ dst,
                            const int* __restrict__ rowptr, const int* __restrict__ slot,
                            int* __restrict__ srcs, int E) {
    int e = blockIdx.x * blockDim.x + threadIdx.x;
    if (e < E) srcs[rowptr[dst[e]] + slot[e]] = src[e];
}

// ---------------- bf16 MFMA GEMM: C[M,256] = A[M,256] @ W ----------------
// block = 4 waves; wave -> 32 rows (2 m-tiles) x full 256 cols (16 n-tiles).

__global__ __launch_bounds__(256, 2) void mfma_gemm(const unsigned short* __restrict__ A,
                                                    const unsigned short* __restrict__ Bp,
                                                    unsigned short* __restrict__ C, int M) {
    const int wave = threadIdx.x >> 6;
    const int lane = threadIdx.x & 63;
    const int quad = lane >> 4;
    const int m    = lane & 15;
    const int row0 = blockIdx.x * 128 + wave * 32;

    const short* arow0 = (const short*)A + (size_t)(row0 + m) * FDIM + quad * 8;
    const short* arow1 = arow0 + 16 * FDIM;

    floatx4 acc0[16], acc1[16];
#pragma unroll
    for (int i = 0; i < 16; i++) {
        acc0[i] = (floatx4){0.f, 0.f, 0.f, 0.f};
        acc1[i] = (floatx4){0.f, 0.f, 0.f, 0.f};
    }

#pragma unroll
    for (int kstep = 0; kstep < 8; kstep++) {
        short8 a0 = *(const short8*)(arow0 + kstep * 32);
        short8 a1 = *(const short8*)(arow1 + kstep * 32);
#pragma unroll
        for (int nt = 0; nt < 16; nt++) {
            short8 b = *(const short8*)((const short*)Bp +
                         ((size_t)(kstep * 16 + nt) * 64 + lane) * 8);
            acc0[nt] = __builtin_amdgcn_mfma_f32_16x16x32_bf16(a0, b, acc0[nt], 0, 0, 0);
            acc1[nt] = __builtin_amdgcn_mfma_f32_16x16x32_bf16(a1, b, acc1[nt], 0, 0, 0);
        }
    }

#pragma unroll
    for (int nt = 0; nt < 16; nt++) {
        int col = nt * 16 + m;
#pragma unroll
        for (int r = 0; r < 4; r++) {
            int row = row0 + quad * 4 + r;
            if (row < M)      C[(size_t)row * FDIM + col]        = f2bf(acc0[nt][r]);
            if (row + 16 < M) C[(size_t)(row + 16) * FDIM + col] = f2bf(acc1[nt][r]);
        }
    }
}

// ---------------- fp32-A MFMA GEMM (layer 0: reads x directly, no cast pass) ----------------

__global__ __launch_bounds__(256, 2) void mfma_gemm_f32(const float* __restrict__ A,
                                                        const unsigned short* __restrict__ Bp,
                                                        unsigned short* __restrict__ C, int M) {
    const int wave = threadIdx.x >> 6;
    const int lane = threadIdx.x & 63;
    const int quad = lane >> 4;
    const int m    = lane & 15;
    const int row0 = blockIdx.x * 128 + wave * 32;

    // clamp row indices: x has exactly M rows (no padding)
    const int r0 = min(row0 + m, M - 1);
    const int r1 = min(row0 + 16 + m, M - 1);
    const float* arow0 = A + (size_t)r0 * FDIM + quad * 8;
    const float* arow1 = A + (size_t)r1 * FDIM + quad * 8;

    floatx4 acc0[16], acc1[16];
#pragma unroll
    for (int i = 0; i < 16; i++) {
        acc0[i] = (floatx4){0.f, 0.f, 0.f, 0.f};
        acc1[i] = (floatx4){0.f, 0.f, 0.f, 0.f};
    }

#pragma unroll
    for (int kstep = 0; kstep < 8; kstep++) {
        float4 p00 = *(const float4*)(arow0 + kstep * 32);
        float4 p01 = *(const float4*)(arow0 + kstep * 32 + 4);
        float4 p10 = *(const float4*)(arow1 + kstep * 32);
        float4 p11 = *(const float4*)(arow1 + kstep * 32 + 4);
        short8 a0, a1;
        a0[0] = (short)f2bf(p00.x); a0[1] = (short)f2bf(p00.y);
        a0[2] = (short)f2bf(p00.z); a0[3] = (short)f2bf(p00.w);
        a0[4] = (short)f2bf(p01.x); a0[5] = (short)f2bf(p01.y);
        a0[6] = (short)f2bf(p01.z); a0[7] = (short)f2bf(p01.w);
        a1[0] = (short)f2bf(p10.x); a1[1] = (short)f2bf(p10.y);
        a1[2] = (short)f2bf(p10.z); a1[3] = (short)f2bf(p10.w);
        a1[4] = (short)f2bf(p11.x); a1[5] = (short)f2bf(p11.y);
        a1[6] = (short)f2bf(p11.z); a1[7] = (short)f2bf(p11.w);
#pragma unroll
        for (int nt = 0; nt < 16; nt++) {
            short8 b = *(const short8*)((const short*)Bp +
                         ((size_t)(kstep * 16 + nt) * 64 + lane) * 8);
            acc0[nt] = __builtin_amdgcn_mfma_f32_16x16x32_bf16(a0, b, acc0[nt], 0, 0, 0);
            acc1[nt] = __builtin_amdgcn_mfma_f32_16x16x32_bf16(a1, b, acc1[nt], 0, 0, 0);
        }
    }

#pragma unroll
    for (int nt = 0; nt < 16; nt++) {
        int col = nt * 16 + m;
#pragma unroll
        for (int r = 0; r < 4; r++) {
            int row = row0 + quad * 4 + r;
            if (row < M)      C[(size_t)row * FDIM + col]        = f2bf(acc0[nt][r]);
            if (row + 16 < M) C[(size_t)(row + 16) * FDIM + col] = f2bf(acc1[nt][r]);
        }
    }
}

// ---------------- gather core (shared by plain and pooling variants) ----------------
// half-wave (32 lanes) per dst node; lane = 8 feats (16B). Edge loop unrolled x4.

static __device__ __forceinline__ void accum8(float* acc, uint4 v, float nm) {
    const unsigned* u = (const unsigned*)&v;
#pragma unroll
    for (int i = 0; i < 4; i++) {
        acc[2 * i]     += nm * __uint_as_float(u[i] << 16);
        acc[2 * i + 1] += nm * __uint_as_float(u[i] & 0xFFFF0000u);
    }
}

static __device__ __forceinline__ void gather_node(const unsigned short* __restrict__ h,
                                                   const int* __restrict__ rowptr,
                                                   const int* __restrict__ srcs,
                                                   const float* __restrict__ dinv,
                                                   const float* __restrict__ bias,
                                                   int node, int lane, float* acc) {
    const float di = dinv[node];
    {
        uint4 sv = *(const uint4*)(h + (size_t)node * FDIM + lane * 8);
        const unsigned* u = (const unsigned*)&sv;
#pragma unroll
        for (int i = 0; i < 4; i++) {
            acc[2 * i]     = di * di * __uint_as_float(u[i] << 16);
            acc[2 * i + 1] = di * di * __uint_as_float(u[i] & 0xFFFF0000u);
        }
        float4 b0 = *(const float4*)(bias + lane * 8);
        float4 b1 = *(const float4*)(bias + lane * 8 + 4);
        acc[0] += b0.x; acc[1] += b0.y; acc[2] += b0.z; acc[3] += b0.w;
        acc[4] += b1.x; acc[5] += b1.y; acc[6] += b1.z; acc[7] += b1.w;
    }
    const int beg = rowptr[node];
    const int end = rowptr[node + 1];
    int p = beg;
    for (; p + 4 <= end; p += 4) {
        int s0 = srcs[p], s1 = srcs[p + 1], s2 = srcs[p + 2], s3 = srcs[p + 3];
        float n0 = dinv[s0] * di, n1 = dinv[s1] * di;
        float n2 = dinv[s2] * di, n3 = dinv[s3] * di;
        uint4 v0 = *(const uint4*)(h + (size_t)s0 * FDIM + lane * 8);
        uint4 v1 = *(const uint4*)(h + (size_t)s1 * FDIM + lane * 8);
        uint4 v2 = *(const uint4*)(h + (size_t)s2 * FDIM + lane * 8);
        uint4 v3 = *(const uint4*)(h + (size_t)s3 * FDIM + lane * 8);
        accum8(acc, v0, n0);
        accum8(acc, v1, n1);
        accum8(acc, v2, n2);
        accum8(acc, v3, n3);
    }
    for (; p < end; p++) {
        int s = srcs[p];
        float nm = dinv[s] * di;
        uint4 v = *(const uint4*)(h + (size_t)s * FDIM + lane * 8);
        accum8(acc, v, nm);
    }
#pragma unroll
    for (int i = 0; i < 8; i++) acc[i] = fmaxf(acc[i], 0.0f);
}

__global__ __launch_bounds__(256) void gather_kernel(const unsigned short* __restrict__ h,
                                                     const int* __restrict__ rowptr,
                                                     const int* __restrict__ srcs,
                                                     const float* __restrict__ dinv,
                                                     const float* __restrict__ bias,
                                                     unsigned short* __restrict__ out, int N) {
    const int node = blockIdx.x * 8 + (threadIdx.x >> 5);
    const int lane = threadIdx.x & 31;
    if (node >= N) return;
    float acc[8];
    gather_node(h, rowptr, srcs, dinv, bias, node, lane, acc);
    unsigned short o[8];
#pragma unroll
    for (int i = 0; i < 8; i++) o[i] = f2bf(acc[i]);
    *(uint4*)(out + (size_t)node * FDIM + lane * 8) = *(uint4*)o;
}

// layer-2 variant: fold global-add-pool in — no state write, accumulate to g.
__global__ __launch_bounds__(256) void gather_pool_kernel(const unsigned short* __restrict__ h,
                                                          const int* __restrict__ rowptr,
                                                          const int* __restrict__ srcs,
                                                          const float* __restrict__ dinv,
                                                          const float* __restrict__ bias,
                                                          const int* __restrict__ batch,
                                                          float* __restrict__ g, int N) {
    __shared__ float red[8][FDIM];   // 8 KB
    __shared__ int bid[8];
    const int hw   = threadIdx.x >> 5;
    const int lane = threadIdx.x & 31;
    const int node = blockIdx.x * 8 + hw;

    float acc[8] = {0.f, 0.f, 0.f, 0.f, 0.f, 0.f, 0.f, 0.f};
    if (node < N) gather_node(h, rowptr, srcs, dinv, bias, node, lane, acc);
#pragma unroll
    for (int i = 0; i < 8; i++) red[hw][lane * 8 + i] = acc[i];
    if (lane == 0) bid[hw] = (node < N) ? batch[node] : -1;
    __syncthreads();

    // per-feature run-length flush over the block's 8 (sorted-batch) nodes
    const int f = threadIdx.x;
    int cur = -1;
    float run = 0.0f;
    for (int i = 0; i < 8; i++) {
        int b = bid[i];
        if (b < 0) break;                    // only trailing rows can be invalid
        if (b != cur) {
            if (cur >= 0) atomicAdd(&g[(size_t)cur * FDIM + f], run);
            cur = b;
            run = 0.0f;
        }
        run += red[i][f];
    }
    if (cur >= 0) atomicAdd(&g[(size_t)cur * FDIM + f], run);
}

// ---------------- fused FC head: FC1 + relu + FC2 + log_softmax ----------------

__global__ __launch_bounds__(256) void fc_head_kernel(const float* __restrict__ g,
                                                      const float* __restrict__ fc1W,
                                                      const float* __restrict__ fc1b,
                                                      const float* __restrict__ fc2W,
                                                      const float* __restrict__ fc2b,
                                                      float* __restrict__ out) {
    __shared__ float gs[FDIM];
    __shared__ float part[4][FDIM];
    __shared__ float hs[FDIM];
    __shared__ float p2[256];
    __shared__ float logits[NCLASS];
    const int r = blockIdx.x;
    const int t = threadIdx.x;
    const int w = t >> 6;
    const int l = t & 63;

    gs[t] = g[(size_t)r * FDIM + t];
    __syncthreads();

    float a[4] = {0.f, 0.f, 0.f, 0.f};
    for (int kk = 0; kk < 64; kk++) {
        int k = w * 64 + kk;
        float gv = gs[k];
#pragma unroll
        for (int j = 0; j < 4; j++) a[j] += gv * fc1W[(size_t)k * FDIM + j * 64 + l];
    }
#pragma unroll
    for (int j = 0; j < 4; j++) part[w][j * 64 + l] = a[j];
    __syncthreads();

    float s1 = part[0][t] + part[1][t] + part[2][t] + part[3][t] + fc1b[t];
    hs[t] = fmaxf(s1, 0.0f);
    __syncthreads();

    float a2 = 0.0f;
    const int c = t & 15;
    if (c < NCLASS) {
        int k0 = (t >> 4) * 16;
        for (int kk = 0; kk < 16; kk++)
            a2 += hs[k0 + kk] * fc2W[(size_t)(k0 + kk) * NCLASS + c];
    }
    p2[t] = a2;
    __syncthreads();

    if (t < NCLASS) {
        float s2 = fc2b[t];
        for (int seg = 0; seg < 16; seg++) s2 += p2[seg * 16 + t];
        logits[t] = s2;
    }
    __syncthreads();

    if (t == 0) {
        float mx = logits[0];
        for (int cc = 1; cc < NCLASS; cc++) mx = fmaxf(mx, logits[cc]);
        float ssum = 0.0f;
        for (int cc = 0; cc < NCLASS; cc++) ssum += expf(logits[cc] - mx);
        float lse = mx + logf(ssum);
        for (int cc = 0; cc < NCLASS; cc++) out[(size_t)r * NCLASS + cc] = logits[cc] - lse;
    }
}

// ---------------- launcher ----------------

extern "C" void kernel_launch(void* const* d_in, const int* in_sizes, int n_in,
                              void* d_out, int out_size, void* d_ws, size_t ws_size,
                              hipStream_t stream) {
    const float* x     = (const float*)d_in[0];
    const int*   ei    = (const int*)d_in[1];
    const int*   batch = (const int*)d_in[2];
    const float* W0 = (const float*)d_in[3];  const float* b0 = (const float*)d_in[4];
    const float* W1 = (const float*)d_in[5];  const float* b1 = (const float*)d_in[6];
    const float* W2 = (const float*)d_in[7];  const float* b2 = (const float*)d_in[8];
    const float* fc1W = (const float*)d_in[9];  const float* fc1b = (const float*)d_in[10];
    const float* fc2W = (const float*)d_in[11]; const float* fc2b = (const float*)d_in[12];
    float* out = (float*)d_out;

    const int N = in_sizes[0] / FDIM;
    const int E = in_sizes[1] / 2;
    const int* src = ei;
    const int* dst = ei + E;
    const int Mpad = ((N + 127) / 128) * 128;
    const int nb   = (N + 1023) / 1024;
    const int nCnt = (E + 255) / 256;

    // workspace layout (16B-aligned chunks)
    char* p = (char*)d_ws;
    unsigned short* S  = (unsigned short*)p; p += (size_t)Mpad * FDIM * 2;  // node state
    unsigned short* H  = (unsigned short*)p; p += (size_t)Mpad * FDIM * 2;  // GEMM out
    unsigned short* Wp0 = (unsigned short*)p; p += (size_t)8192 * 8 * 2;
    unsigned short* Wp1 = (unsigned short*)p; p += (size_t)8192 * 8 * 2;
    unsigned short* Wp2 = (unsigned short*)p; p += (size_t)8192 * 8 * 2;
    float* dinv = (float*)p; p += (size_t)N * 4;
    int*   cnt  = (int*)p;   p += (size_t)N * 4;
    int*   rowptr = (int*)p; p += (size_t)(N + 4) * 4;
    int*   bsum = (int*)p;   p += (size_t)256 * 4;
    int*   srcs = (int*)p;   p += (size_t)E * 4;
    int*   slot = (int*)p;   p += (size_t)E * 4;
    float* g    = (float*)p;

    // ---- prep: zero cnt, then count+slot | packw | zero-g ----
    hipMemsetAsync(cnt, 0, (size_t)N * sizeof(int), stream);
    prep_kernel<<<nCnt + 128, 256, 0, stream>>>(dst, cnt, slot, E, nCnt,
                                                W0, W1, W2, Wp0, Wp1, Wp2, (float4*)g);

    // ---- CSR scan + fill ----
    csr_bsum<<<nb, 256, 0, stream>>>(cnt, bsum, N);
    csr_bscan<<<1, 256, 0, stream>>>(bsum, nb);
    csr_scan2<<<nb, 256, 0, stream>>>(cnt, bsum, rowptr, dinv, N, E);
    fill_kernel<<<(E + 255) / 256, 256, 0, stream>>>(src, dst, rowptr, slot, srcs, E);

    // ---- 3 GCN layers ----
    const int ng = (N + 127) / 128;
    mfma_gemm_f32<<<ng, 256, 0, stream>>>(x, Wp0, H, N);
    gather_kernel<<<(N + 7) / 8, 256, 0, stream>>>(H, rowptr, srcs, dinv, b0, S, N);
    mfma_gemm<<<ng, 256, 0, stream>>>(S, Wp1, H, N);
    gather_kernel<<<(N + 7) / 8, 256, 0, stream>>>(H, rowptr, srcs, dinv, b1, S, N);
    mfma_gemm<<<ng, 256, 0, stream>>>(S, Wp2, H, N);
    gather_pool_kernel<<<(N + 7) / 8, 256, 0, stream>>>(H, rowptr, srcs, dinv, b2,
                                                        batch, g, N);

    // ---- head ----
    fc_head_kernel<<<NGRAPH, 256, 0, stream>>>(g, fc1W, fc1b, fc2W, fc2b, out);
}